// Round 4
// baseline (430.028 us; speedup 1.0000x reference)
//
#include <hip/hip_runtime.h>
#include <cstdint>
#include <cstddef>

#define NUSER 100000
#define NITEM 50000
#define NTOT  150000          // NITEM + NUSER (item rows first, then user rows)
#define NEDGE 500000
#define NEG_SLOPE 0.01f
#define PADW 136              // 128 + 8 bf16 pad (16B) -> conflict-free ds_read_b128

#define BSHIFT 7
#define BROWS 128                                  // rows per bucket
#define NBUCK ((NTOT + BROWS - 1) / BROWS)         // 1172
#define BCAP 2048                                  // cap per bucket (mean 853, ~41 sigma)

typedef __attribute__((ext_vector_type(8))) short bf16x8;
typedef __attribute__((ext_vector_type(4))) float f32x4;

__device__ __forceinline__ unsigned short f2bf(float f) {
    unsigned int u = __builtin_bit_cast(unsigned int, f);
    unsigned int r = u + 0x7fffu + ((u >> 16) & 1u);   // RNE
    return (unsigned short)(r >> 16);
}
__device__ __forceinline__ float bf2f(unsigned int b) {
    unsigned int u = (b & 0xffffu) << 16;
    return __builtin_bit_cast(float, u);
}
__device__ __forceinline__ unsigned int pack2(float lo, float hi) {
    return (unsigned int)f2bf(lo) | ((unsigned int)f2bf(hi) << 16);
}

// ---------------- CSR build: bucketed counting sort ----------------
// entry = (row&127)<<17 | src   (src < 2^17)

__global__ void bin_edges(const int* __restrict__ src_rates, const int* __restrict__ dst_rates,
                          const int* __restrict__ src_rev,   const int* __restrict__ dst_rev,
                          int* __restrict__ bcnt, unsigned int* __restrict__ bbuf) {
    int e = blockIdx.x * blockDim.x + threadIdx.x;
    if (e >= NEDGE) return;
    int r1 = dst_rates[e];
    int b1 = r1 >> BSHIFT;
    int p1 = atomicAdd(&bcnt[b1], 1);
    bbuf[(size_t)b1 * BCAP + p1] = ((unsigned)(r1 & (BROWS - 1)) << 17) | (unsigned)src_rates[e];
    int r2 = NITEM + dst_rev[e];
    int b2 = r2 >> BSHIFT;
    int p2 = atomicAdd(&bcnt[b2], 1);
    bbuf[(size_t)b2 * BCAP + p2] = ((unsigned)(r2 & (BROWS - 1)) << 17) | (unsigned)src_rev[e];
}

// single block: exclusive scan of NBUCK bucket counts -> bbase
__global__ __launch_bounds__(256) void bscan(const int* __restrict__ bcnt, int* __restrict__ bbase) {
    __shared__ int sm[256];
    int t = threadIdx.x;
    const int C = (NBUCK + 255) / 256;   // 5
    int beg = t * C;
    int end = beg + C; if (end > NBUCK) end = NBUCK;
    int s = 0;
    for (int j = beg; j < end; ++j) s += bcnt[j];
    sm[t] = s;
    __syncthreads();
    for (int off = 1; off < 256; off <<= 1) {
        int x = (t >= off) ? sm[t - off] : 0;
        __syncthreads();
        sm[t] += x;
        __syncthreads();
    }
    int run = sm[t] - s;
    for (int j = beg; j < end; ++j) {
        int v = bcnt[j];
        bbase[j] = run;
        run += v;
    }
}

// one block per bucket: LDS histogram -> rp, then LDS-cursor scatter -> csr
__global__ __launch_bounds__(256) void build_csr(const int* __restrict__ bcnt, const int* __restrict__ bbase,
                                                 const unsigned int* __restrict__ bbuf,
                                                 int* __restrict__ rp, int* __restrict__ csr) {
    __shared__ unsigned int ent[BCAP];
    __shared__ int h[BROWS], hs[BROWS];
    int bk = blockIdx.x, t = threadIdx.x;
    int n = bcnt[bk];
    int base = bbase[bk];
    const unsigned int* src = bbuf + (size_t)bk * BCAP;
    for (int i = t; i < n; i += 256) ent[i] = src[i];
    if (t < BROWS) h[t] = 0;
    __syncthreads();
    for (int i = t; i < n; i += 256) atomicAdd(&h[ent[i] >> 17], 1);
    __syncthreads();
    int v = (t < BROWS) ? h[t] : 0;
    if (t < BROWS) hs[t] = v;
    __syncthreads();
    for (int off = 1; off < BROWS; off <<= 1) {
        int x = (t < BROWS && t >= off) ? hs[t - off] : 0;
        __syncthreads();
        if (t < BROWS) hs[t] += x;
        __syncthreads();
    }
    if (t < BROWS) hs[t] -= v;          // exclusive
    if (t < BROWS) h[t] = 0;            // reuse as scatter cursors
    __syncthreads();
    int row = bk * BROWS + t;
    if (t < BROWS && row < NTOT) rp[row] = base + hs[t];
    if (bk == 0 && t == 0) rp[NTOT] = 2 * NEDGE;
    for (int i = t; i < n; i += 256) {
        unsigned int ev = ent[i];
        int rl = (int)(ev >> 17);
        int pos = base + hs[rl] + atomicAdd(&h[rl], 1);
        csr[pos] = (int)(ev & 0x1FFFFu);
    }
}

// ---------------- weight prep: W[128][128] fp32 -> Wt bf16 [col][k] padded PADW ----------------

__global__ void wprep(const float* __restrict__ w0, const float* __restrict__ w1,
                      const float* __restrict__ w2, const float* __restrict__ w3,
                      unsigned short* __restrict__ wt) {
    const float* src = (blockIdx.x == 0) ? w0 : (blockIdx.x == 1) ? w1 : (blockIdx.x == 2) ? w2 : w3;
    unsigned short* dst = wt + (size_t)blockIdx.x * 128 * PADW;
    for (int i = threadIdx.x; i < 16384; i += 256) {
        int k = i >> 7, c = i & 127;
        dst[c * PADW + k] = f2bf(src[i]);
    }
}

// ---------------- x -> bf16 convert (both feature tables, one launch) ----------------

__global__ void cvt_bf(const float* __restrict__ xu, const float* __restrict__ xi,
                       unsigned short* __restrict__ dst) {
    const int n8u = NUSER * 128 / 8;
    const int n8  = (NUSER + NITEM) * 128 / 8;
    for (int i = blockIdx.x * blockDim.x + threadIdx.x; i < n8; i += gridDim.x * blockDim.x) {
        const float* s = (i < n8u) ? (xu + (size_t)i * 8) : (xi + (size_t)(i - n8u) * 8);
        float4 a = ((const float4*)s)[0];
        float4 b = ((const float4*)s)[1];
        uint4 o;
        o.x = pack2(a.x, a.y);
        o.y = pack2(a.z, a.w);
        o.z = pack2(b.x, b.y);
        o.w = pack2(b.z, b.w);
        ((uint4*)dst)[i] = o;
    }
}

// ---------------- aggregation (bf16 in -> bf16 out), both relations in one grid ----------------

__global__ __launch_bounds__(256) void aggregate_bf(const unsigned short* __restrict__ featA,  // item rows
                                                    const unsigned short* __restrict__ featB,  // user rows
                                                    const int* __restrict__ rp, const int* __restrict__ csr,
                                                    unsigned short* __restrict__ outb) {
    int row = blockIdx.x * 8 + (threadIdx.x >> 5);
    if (row >= NTOT) return;
    const unsigned short* feat = (row < NITEM) ? featA : featB;
    int l = threadIdx.x & 31;
    int sub = l >> 4, l16 = l & 15;
    int b = rp[row], e = rp[row + 1];
    float a0 = 0.f, a1 = 0.f, a2 = 0.f, a3 = 0.f, a4 = 0.f, a5 = 0.f, a6 = 0.f, a7 = 0.f;
    for (int j = b + sub; j < e; j += 2) {
        int s = csr[j];
        uint4 v = *((const uint4*)(feat + (size_t)s * 128) + l16);
        a0 += bf2f(v.x); a1 += bf2f(v.x >> 16);
        a2 += bf2f(v.y); a3 += bf2f(v.y >> 16);
        a4 += bf2f(v.z); a5 += bf2f(v.z >> 16);
        a6 += bf2f(v.w); a7 += bf2f(v.w >> 16);
    }
    a0 += __shfl_xor(a0, 16); a1 += __shfl_xor(a1, 16);
    a2 += __shfl_xor(a2, 16); a3 += __shfl_xor(a3, 16);
    a4 += __shfl_xor(a4, 16); a5 += __shfl_xor(a5, 16);
    a6 += __shfl_xor(a6, 16); a7 += __shfl_xor(a7, 16);
    if (sub == 0) {
        int deg = e - b;
        float inv = 1.0f / (float)(deg > 0 ? deg : 1);
        uint4 o;
        o.x = pack2(a0 * inv, a1 * inv);
        o.y = pack2(a2 * inv, a3 * inv);
        o.z = pack2(a4 * inv, a5 * inv);
        o.w = pack2(a6 * inv, a7 * inv);
        *((uint4*)(outb + (size_t)row * 128) + l16) = o;
    }
}

// ---------------- MFMA GEMM: out[N][128] = bf16 in[N][128] @ W + bias (+leaky) ----------------

__global__ __launch_bounds__(256) void gemm_mfma(const unsigned short* __restrict__ in,
                                                 const unsigned short* __restrict__ wt,
                                                 const float* __restrict__ bias,
                                                 float* __restrict__ outF,             // fp32 path if non-null
                                                 unsigned short* __restrict__ outB,    // bf16 path otherwise
                                                 int N, int leaky) {
    __shared__ __attribute__((aligned(16))) unsigned short wl[128 * PADW];
    __shared__ __attribute__((aligned(16))) unsigned short xl[64 * PADW];
    int t = threadIdx.x;
    int row0 = blockIdx.x * 64;

    for (int i = t; i < 128 * PADW / 8; i += 256)
        ((uint4*)wl)[i] = ((const uint4*)wt)[i];

    for (int i = t; i < 1024; i += 256) {
        int r = i >> 4, c = i & 15;
        int row = row0 + r;
        uint4 v = make_uint4(0u, 0u, 0u, 0u);
        if (row < N) v = ((const uint4*)(in + (size_t)row * 128))[c];
        ((uint4*)xl)[r * (PADW / 8) + c] = v;
    }
    __syncthreads();

    int lane = t & 63, w = t >> 6;
    int l16 = lane & 15, kq = lane >> 4;
    int rowb = w * 16;

    f32x4 acc[8];
    #pragma unroll
    for (int i = 0; i < 8; ++i) acc[i] = (f32x4){0.f, 0.f, 0.f, 0.f};

    #pragma unroll
    for (int ks = 0; ks < 4; ++ks) {
        int ko = ks * 32 + kq * 8;
        bf16x8 af = *(const bf16x8*)&xl[(rowb + l16) * PADW + ko];
        #pragma unroll
        for (int t8 = 0; t8 < 8; ++t8) {
            bf16x8 bf = *(const bf16x8*)&wl[(t8 * 16 + l16) * PADW + ko];
            acc[t8] = __builtin_amdgcn_mfma_f32_16x16x32_bf16(af, bf, acc[t8], 0, 0, 0);
        }
    }

    float bv[8];
    #pragma unroll
    for (int t8 = 0; t8 < 8; ++t8) bv[t8] = bias[t8 * 16 + l16];

    if (outF) {
        #pragma unroll
        for (int t8 = 0; t8 < 8; ++t8) {
            #pragma unroll
            for (int j = 0; j < 4; ++j) {
                int row = row0 + rowb + kq * 4 + j;
                if (row < N) {
                    float v = acc[t8][j] + bv[t8];
                    if (leaky) v = v > 0.f ? v : NEG_SLOPE * v;
                    outF[(size_t)row * 128 + t8 * 16 + l16] = v;
                }
            }
        }
    } else {
        #pragma unroll
        for (int t8 = 0; t8 < 8; ++t8) {
            #pragma unroll
            for (int j = 0; j < 4; ++j) {
                float v = acc[t8][j] + bv[t8];
                if (leaky) v = v > 0.f ? v : NEG_SLOPE * v;
                xl[(rowb + kq * 4 + j) * PADW + t8 * 16 + l16] = f2bf(v);
            }
        }
        __syncthreads();
        for (int i = t; i < 1024; i += 256) {
            int r = i >> 4, c = i & 15;
            int row = row0 + r;
            if (row < N)
                ((uint4*)(outB + (size_t)row * 128))[c] = ((uint4*)xl)[r * (PADW / 8) + c];
        }
    }
}

// ---------------- launch ----------------

extern "C" void kernel_launch(void* const* d_in, const int* in_sizes, int n_in,
                              void* d_out, int out_size, void* d_ws, size_t ws_size,
                              hipStream_t stream) {
    const float* x_user    = (const float*)d_in[0];
    const float* x_item    = (const float*)d_in[1];
    const int*   src_rates = (const int*)d_in[2];
    const int*   dst_rates = (const int*)d_in[3];
    const int*   src_rev   = (const int*)d_in[4];
    const int*   dst_rev   = (const int*)d_in[5];
    const float* W1_rates  = (const float*)d_in[6];
    const float* b1_rates  = (const float*)d_in[7];
    const float* W1_rev    = (const float*)d_in[8];
    const float* b1_rev    = (const float*)d_in[9];
    const float* W2_rates  = (const float*)d_in[10];
    const float* b2_rates  = (const float*)d_in[11];
    const float* W2_rev    = (const float*)d_in[12];
    const float* b2_rev    = (const float*)d_in[13];

    float* out    = (float*)d_out;
    float* o_user = out;                          // [NUSER,128] fp32
    float* o_item = out + (size_t)NUSER * 128;    // [NITEM,128] fp32

    char* ws = (char*)d_ws;
    size_t off = 0;
    auto carve = [&](size_t bytes) -> void* {
        void* p = ws + off;
        off = (off + bytes + 255) & ~(size_t)255;
        return p;
    };
    // A: first x_bf {xu[NU],xi[NI]}, later h {h_item[NI], h_user[NU]}
    unsigned short* A = (unsigned short*)carve((size_t)NTOT * 128 * 2);
    // B: aggregate output; ALSO overlaid by bucket buffer during CSR build (9.6MB < 38.4MB)
    unsigned short* B = (unsigned short*)carve((size_t)NTOT * 128 * 2);
    int* rp    = (int*)carve((size_t)(NTOT + 1) * 4);
    int* bcnt  = (int*)carve((size_t)NBUCK * 4);
    int* bbase = (int*)carve((size_t)NBUCK * 4);
    int* csr   = (int*)carve((size_t)(2 * NEDGE) * 4);
    unsigned short* wtAll = (unsigned short*)carve((size_t)4 * 128 * PADW * 2);
    unsigned short* Wt1_rates = wtAll;
    unsigned short* Wt1_rev   = wtAll + 1 * (size_t)128 * PADW;
    unsigned short* Wt2_rates = wtAll + 2 * (size_t)128 * PADW;
    unsigned short* Wt2_rev   = wtAll + 3 * (size_t)128 * PADW;

    unsigned int* bbuf = (unsigned int*)B;        // overlay: consumed before aggregate writes B

    unsigned short* xu_bf = A;
    unsigned short* xi_bf = A + (size_t)NUSER * 128;
    unsigned short* h_item = A;
    unsigned short* h_user = A + (size_t)NITEM * 128;
    unsigned short* agg_item = B;
    unsigned short* agg_user = B + (size_t)NITEM * 128;

    // --- CSR build (bucketed counting sort) ---
    hipMemsetAsync(bcnt, 0, (size_t)NBUCK * 4, stream);
    int eb = (NEDGE + 255) / 256;
    bin_edges<<<eb, 256, 0, stream>>>(src_rates, dst_rates, src_rev, dst_rev, bcnt, bbuf);
    bscan<<<1, 256, 0, stream>>>(bcnt, bbase);
    build_csr<<<NBUCK, 256, 0, stream>>>(bcnt, bbase, bbuf, rp, csr);

    // --- prep: weights + feature bf16 ---
    wprep<<<4, 256, 0, stream>>>(W1_rates, W1_rev, W2_rates, W2_rev, wtAll);
    cvt_bf<<<2048, 256, 0, stream>>>(x_user, x_item, A);

    int nbI = (NITEM + 63) / 64, nbU = (NUSER + 63) / 64;
    int nbAgg = (NTOT + 7) / 8;

    // --- layer 1 ---
    aggregate_bf<<<nbAgg, 256, 0, stream>>>(xu_bf, xi_bf, rp, csr, B);
    gemm_mfma<<<nbI, 256, 0, stream>>>(agg_item, Wt1_rates, b1_rates, nullptr, h_item, NITEM, 1);
    gemm_mfma<<<nbU, 256, 0, stream>>>(agg_user, Wt1_rev,   b1_rev,   nullptr, h_user, NUSER, 1);

    // --- layer 2 ---
    aggregate_bf<<<nbAgg, 256, 0, stream>>>(h_user, h_item, rp, csr, B);
    gemm_mfma<<<nbI, 256, 0, stream>>>(agg_item, Wt2_rates, b2_rates, o_item, nullptr, NITEM, 0);
    gemm_mfma<<<nbU, 256, 0, stream>>>(agg_user, Wt2_rev,   b2_rev,   o_user, nullptr, NUSER, 0);
}

// Round 7
// 280.173 us; speedup vs baseline: 1.5349x; 1.5349x over previous
//
#include <hip/hip_runtime.h>
#include <cstdint>
#include <cstddef>

#define NUSER 100000
#define NITEM 50000
#define NTOT  150000          // NITEM + NUSER (item rows first, then user rows)
#define NEDGE 500000
#define NEG_SLOPE 0.01f
#define PADW 136              // 128 + 8 bf16 pad (16B) -> conflict-free ds_read_b128

// ---- bucketed CSR build params ----
// Item rows have mean degree 10 (500k/50k), user rows 5. Worst bucket = item:
// 512 rows * 10 = 5120 mean, sigma ~71  ->  GCAP 8192 is +43 sigma. No overflow.
#define BROWS 512                                  // rows per bucket
#define BSHIFT 9
#define NBUCK ((NTOT + BROWS - 1) / BROWS)         // 293
#define GCAP  8192                                 // global cap per bucket
#define EPB   4096                                 // edges per bin block
#define NBINB ((NEDGE + EPB - 1) / EPB)            // 123
#define NENT  (2 * EPB)                            // entries per bin block (both relations)

typedef __attribute__((ext_vector_type(8))) short bf16x8;
typedef __attribute__((ext_vector_type(4))) float f32x4;

__device__ __forceinline__ unsigned short f2bf(float f) {
    unsigned int u = __builtin_bit_cast(unsigned int, f);
    unsigned int r = u + 0x7fffu + ((u >> 16) & 1u);   // RNE
    return (unsigned short)(r >> 16);
}
__device__ __forceinline__ float bf2f(unsigned int b) {
    unsigned int u = (b & 0xffffu) << 16;
    return __builtin_bit_cast(float, u);
}
__device__ __forceinline__ unsigned int pack2(float lo, float hi) {
    return (unsigned int)f2bf(lo) | ((unsigned int)f2bf(hi) << 16);
}

// ---------------- CSR build phase 1: LDS-staged binning ----------------
// entry = (row & 511) << 17 | src    (src < 2^17, row_local < 2^9)

__global__ __launch_bounds__(256) void bin_edges(const int* __restrict__ src_rates, const int* __restrict__ dst_rates,
                                                 const int* __restrict__ src_rev,   const int* __restrict__ dst_rev,
                                                 int* __restrict__ bcnt, unsigned int* __restrict__ bbuf) {
    __shared__ int h[NBUCK];       // per-block bucket counts
    __shared__ int hs[NBUCK];      // staging segment start
    __shared__ int hbase[NBUCK];   // reserved global offset per bucket
    __shared__ int hcur[NBUCK];    // staging cursor
    __shared__ int bsc[256];
    __shared__ unsigned int stage[NENT];

    int t = threadIdx.x;
    int e0 = blockIdx.x * EPB;
    int n = NEDGE - e0; if (n > EPB) n = EPB;

    for (int i = t; i < NBUCK; i += 256) h[i] = 0;
    __syncthreads();

    // pass 1: count
    for (int i = t; i < n; i += 256) {
        int e = e0 + i;
        atomicAdd(&h[dst_rates[e] >> BSHIFT], 1);
        atomicAdd(&h[(NITEM + dst_rev[e]) >> BSHIFT], 1);
    }
    __syncthreads();

    // local exclusive scan over NBUCK (2 elements/thread) + reserve global segments
    int i0 = 2 * t, i1 = 2 * t + 1;
    int v0 = (i0 < NBUCK) ? h[i0] : 0;
    int v1 = (i1 < NBUCK) ? h[i1] : 0;
    int ls = v0 + v1;
    bsc[t] = ls;
    __syncthreads();
    for (int off = 1; off < 256; off <<= 1) {
        int x = (t >= off) ? bsc[t - off] : 0;
        __syncthreads();
        bsc[t] += x;
        __syncthreads();
    }
    int run = bsc[t] - ls;
    if (i0 < NBUCK) {
        hs[i0] = run; hcur[i0] = run;
        hbase[i0] = (v0 > 0) ? atomicAdd(&bcnt[i0], v0) : 0;
    }
    if (i1 < NBUCK) {
        hs[i1] = run + v0; hcur[i1] = run + v0;
        hbase[i1] = (v1 > 0) ? atomicAdd(&bcnt[i1], v1) : 0;
    }
    __syncthreads();

    // pass 2: scatter into LDS staging (bucket-sorted)
    for (int i = t; i < n; i += 256) {
        int e = e0 + i;
        int r1 = dst_rates[e];
        int p1 = atomicAdd(&hcur[r1 >> BSHIFT], 1);
        if (p1 < NENT)
            stage[p1] = ((unsigned)(r1 & (BROWS - 1)) << 17) | (unsigned)src_rates[e];
        int r2 = NITEM + dst_rev[e];
        int p2 = atomicAdd(&hcur[r2 >> BSHIFT], 1);
        if (p2 < NENT)
            stage[p2] = ((unsigned)(r2 & (BROWS - 1)) << 17) | (unsigned)src_rev[e];
    }
    __syncthreads();

    // flush: one wave per bucket (round-robin), contiguous coalesced writes
    int wid = t >> 6, lane = t & 63;
    for (int b = wid; b < NBUCK; b += 4) {
        int cnt = h[b];
        if (cnt > NENT) cnt = NENT;    // defensive clamp
        int gb = hbase[b];
        int sb = hs[b];
        for (int i = lane; i < cnt; i += 64) {
            int gpos = gb + i;
            if (gpos < GCAP) bbuf[(size_t)b * GCAP + gpos] = stage[sb + i];
        }
    }
}

// single block: exclusive scan of NBUCK bucket counts -> bbase (2 elements/thread)
__global__ __launch_bounds__(256) void bscan(const int* __restrict__ bcnt, int* __restrict__ bbase) {
    __shared__ int sm[256];
    int t = threadIdx.x;
    int i0 = 2 * t, i1 = 2 * t + 1;
    int v0 = (i0 < NBUCK) ? bcnt[i0] : 0;
    int v1 = (i1 < NBUCK) ? bcnt[i1] : 0;
    int ls = v0 + v1;
    sm[t] = ls;
    __syncthreads();
    for (int off = 1; off < 256; off <<= 1) {
        int x = (t >= off) ? sm[t - off] : 0;
        __syncthreads();
        sm[t] += x;
        __syncthreads();
    }
    int run = sm[t] - ls;
    if (i0 < NBUCK) bbase[i0] = run;
    if (i1 < NBUCK) bbase[i1] = run + v0;
}

// ---------------- CSR build phase 2: one block per bucket ----------------

__global__ __launch_bounds__(256) void build_csr(const int* __restrict__ bcnt, const int* __restrict__ bbase,
                                                 const unsigned int* __restrict__ bbuf,
                                                 int* __restrict__ rp, int* __restrict__ csr) {
    __shared__ unsigned int ent[GCAP];   // 32 KB
    __shared__ int h[BROWS], hs[BROWS];  // 4 KB (BROWS = 512 = 2*256 exactly)
    __shared__ int bsc[256];

    int bk = blockIdx.x, t = threadIdx.x;
    int base = bbase[bk];                // uniform scalar load
    int n = bcnt[bk];
    if (n > GCAP) n = GCAP;              // defensive (cannot trigger per capacity math)

    const unsigned int* src = bbuf + (size_t)bk * GCAP;
    for (int i = t; i < n; i += 256) ent[i] = src[i];
    h[t] = 0; h[t + 256] = 0;
    __syncthreads();

    // histogram over 512 local rows
    for (int i = t; i < n; i += 256) atomicAdd(&h[ent[i] >> 17], 1);
    __syncthreads();

    // exclusive scan of 512 (2 per thread)
    int v0 = h[2 * t], v1 = h[2 * t + 1];
    int ls = v0 + v1;
    bsc[t] = ls;
    __syncthreads();
    for (int off = 1; off < 256; off <<= 1) {
        int x = (t >= off) ? bsc[t - off] : 0;
        __syncthreads();
        bsc[t] += x;
        __syncthreads();
    }
    int run = bsc[t] - ls;
    hs[2 * t] = run;
    hs[2 * t + 1] = run + v0;
    __syncthreads();

    // write rp (contiguous) and reset cursors
    for (int r = t; r < BROWS; r += 256) {
        int row = bk * BROWS + r;
        if (row < NTOT) rp[row] = base + hs[r];
        h[r] = 0;
    }
    if (bk == 0 && t == 0) rp[NTOT] = 2 * NEDGE;
    __syncthreads();

    // scatter csr within this bucket's contiguous region (single-XCD lines)
    for (int i = t; i < n; i += 256) {
        unsigned int ev = ent[i];
        int rl = (int)(ev >> 17);
        int pos = base + hs[rl] + atomicAdd(&h[rl], 1);
        csr[pos] = (int)(ev & 0x1FFFFu);
    }
}

// ---------------- weight prep: W[128][128] fp32 -> Wt bf16 [col][k] padded PADW ----------------

__global__ void wprep(const float* __restrict__ w0, const float* __restrict__ w1,
                      const float* __restrict__ w2, const float* __restrict__ w3,
                      unsigned short* __restrict__ wt) {
    const float* src = (blockIdx.x == 0) ? w0 : (blockIdx.x == 1) ? w1 : (blockIdx.x == 2) ? w2 : w3;
    unsigned short* dst = wt + (size_t)blockIdx.x * 128 * PADW;
    for (int i = threadIdx.x; i < 16384; i += 256) {
        int k = i >> 7, c = i & 127;
        dst[c * PADW + k] = f2bf(src[i]);
    }
}

// ---------------- x -> bf16 convert ----------------

__global__ void cvt_bf(const float* __restrict__ xu, const float* __restrict__ xi,
                       unsigned short* __restrict__ dst) {
    const int n8u = NUSER * 128 / 8;
    const int n8  = (NUSER + NITEM) * 128 / 8;
    for (int i = blockIdx.x * blockDim.x + threadIdx.x; i < n8; i += gridDim.x * blockDim.x) {
        const float* s = (i < n8u) ? (xu + (size_t)i * 8) : (xi + (size_t)(i - n8u) * 8);
        float4 a = ((const float4*)s)[0];
        float4 b = ((const float4*)s)[1];
        uint4 o;
        o.x = pack2(a.x, a.y);
        o.y = pack2(a.z, a.w);
        o.z = pack2(b.x, b.y);
        o.w = pack2(b.z, b.w);
        ((uint4*)dst)[i] = o;
    }
}

// ---------------- aggregation (bf16 in -> bf16 out), both relations in one grid ----------------

__global__ __launch_bounds__(256) void aggregate_bf(const unsigned short* __restrict__ featA,  // item rows
                                                    const unsigned short* __restrict__ featB,  // user rows
                                                    const int* __restrict__ rp, const int* __restrict__ csr,
                                                    unsigned short* __restrict__ outb) {
    int row = blockIdx.x * 8 + (threadIdx.x >> 5);
    if (row >= NTOT) return;
    const unsigned short* feat = (row < NITEM) ? featA : featB;
    int l = threadIdx.x & 31;
    int sub = l >> 4, l16 = l & 15;
    int b = rp[row], e = rp[row + 1];
    float a0 = 0.f, a1 = 0.f, a2 = 0.f, a3 = 0.f, a4 = 0.f, a5 = 0.f, a6 = 0.f, a7 = 0.f;
    for (int j = b + sub; j < e; j += 2) {
        int s = csr[j];
        uint4 v = *((const uint4*)(feat + (size_t)s * 128) + l16);
        a0 += bf2f(v.x); a1 += bf2f(v.x >> 16);
        a2 += bf2f(v.y); a3 += bf2f(v.y >> 16);
        a4 += bf2f(v.z); a5 += bf2f(v.z >> 16);
        a6 += bf2f(v.w); a7 += bf2f(v.w >> 16);
    }
    a0 += __shfl_xor(a0, 16); a1 += __shfl_xor(a1, 16);
    a2 += __shfl_xor(a2, 16); a3 += __shfl_xor(a3, 16);
    a4 += __shfl_xor(a4, 16); a5 += __shfl_xor(a5, 16);
    a6 += __shfl_xor(a6, 16); a7 += __shfl_xor(a7, 16);
    if (sub == 0) {
        int deg = e - b;
        float inv = 1.0f / (float)(deg > 0 ? deg : 1);
        uint4 o;
        o.x = pack2(a0 * inv, a1 * inv);
        o.y = pack2(a2 * inv, a3 * inv);
        o.z = pack2(a4 * inv, a5 * inv);
        o.w = pack2(a6 * inv, a7 * inv);
        *((uint4*)(outb + (size_t)row * 128) + l16) = o;
    }
}

// ---------------- MFMA GEMM: out[N][128] = bf16 in[N][128] @ W + bias (+leaky) ----------------

__global__ __launch_bounds__(256) void gemm_mfma(const unsigned short* __restrict__ in,
                                                 const unsigned short* __restrict__ wt,
                                                 const float* __restrict__ bias,
                                                 float* __restrict__ outF,             // fp32 path if non-null
                                                 unsigned short* __restrict__ outB,    // bf16 path otherwise
                                                 int N, int leaky) {
    __shared__ __attribute__((aligned(16))) unsigned short wl[128 * PADW];
    __shared__ __attribute__((aligned(16))) unsigned short xl[64 * PADW];
    int t = threadIdx.x;
    int row0 = blockIdx.x * 64;

    for (int i = t; i < 128 * PADW / 8; i += 256)
        ((uint4*)wl)[i] = ((const uint4*)wt)[i];

    for (int i = t; i < 1024; i += 256) {
        int r = i >> 4, c = i & 15;
        int row = row0 + r;
        uint4 v = make_uint4(0u, 0u, 0u, 0u);
        if (row < N) v = ((const uint4*)(in + (size_t)row * 128))[c];
        ((uint4*)xl)[r * (PADW / 8) + c] = v;
    }
    __syncthreads();

    int lane = t & 63, w = t >> 6;
    int l16 = lane & 15, kq = lane >> 4;
    int rowb = w * 16;

    f32x4 acc[8];
    #pragma unroll
    for (int i = 0; i < 8; ++i) acc[i] = (f32x4){0.f, 0.f, 0.f, 0.f};

    #pragma unroll
    for (int ks = 0; ks < 4; ++ks) {
        int ko = ks * 32 + kq * 8;
        bf16x8 af = *(const bf16x8*)&xl[(rowb + l16) * PADW + ko];
        #pragma unroll
        for (int t8 = 0; t8 < 8; ++t8) {
            bf16x8 bf = *(const bf16x8*)&wl[(t8 * 16 + l16) * PADW + ko];
            acc[t8] = __builtin_amdgcn_mfma_f32_16x16x32_bf16(af, bf, acc[t8], 0, 0, 0);
        }
    }

    float bv[8];
    #pragma unroll
    for (int t8 = 0; t8 < 8; ++t8) bv[t8] = bias[t8 * 16 + l16];

    if (outF) {
        #pragma unroll
        for (int t8 = 0; t8 < 8; ++t8) {
            #pragma unroll
            for (int j = 0; j < 4; ++j) {
                int row = row0 + rowb + kq * 4 + j;
                if (row < N) {
                    float v = acc[t8][j] + bv[t8];
                    if (leaky) v = v > 0.f ? v : NEG_SLOPE * v;
                    outF[(size_t)row * 128 + t8 * 16 + l16] = v;
                }
            }
        }
    } else {
        #pragma unroll
        for (int t8 = 0; t8 < 8; ++t8) {
            #pragma unroll
            for (int j = 0; j < 4; ++j) {
                float v = acc[t8][j] + bv[t8];
                if (leaky) v = v > 0.f ? v : NEG_SLOPE * v;
                xl[(rowb + kq * 4 + j) * PADW + t8 * 16 + l16] = f2bf(v);
            }
        }
        __syncthreads();
        for (int i = t; i < 1024; i += 256) {
            int r = i >> 4, c = i & 15;
            int row = row0 + r;
            if (row < N)
                ((uint4*)(outB + (size_t)row * 128))[c] = ((uint4*)xl)[r * (PADW / 8) + c];
        }
    }
}

// ---------------- launch ----------------

extern "C" void kernel_launch(void* const* d_in, const int* in_sizes, int n_in,
                              void* d_out, int out_size, void* d_ws, size_t ws_size,
                              hipStream_t stream) {
    const float* x_user    = (const float*)d_in[0];
    const float* x_item    = (const float*)d_in[1];
    const int*   src_rates = (const int*)d_in[2];
    const int*   dst_rates = (const int*)d_in[3];
    const int*   src_rev   = (const int*)d_in[4];
    const int*   dst_rev   = (const int*)d_in[5];
    const float* W1_rates  = (const float*)d_in[6];
    const float* b1_rates  = (const float*)d_in[7];
    const float* W1_rev    = (const float*)d_in[8];
    const float* b1_rev    = (const float*)d_in[9];
    const float* W2_rates  = (const float*)d_in[10];
    const float* b2_rates  = (const float*)d_in[11];
    const float* W2_rev    = (const float*)d_in[12];
    const float* b2_rev    = (const float*)d_in[13];

    float* out    = (float*)d_out;
    float* o_user = out;                          // [NUSER,128] fp32
    float* o_item = out + (size_t)NUSER * 128;    // [NITEM,128] fp32

    char* ws = (char*)d_ws;
    size_t off = 0;
    auto carve = [&](size_t bytes) -> void* {
        void* p = ws + off;
        off = (off + bytes + 255) & ~(size_t)255;
        return p;
    };
    // A: first x_bf {xu[NU],xi[NI]}, later h {h_item[NI], h_user[NU]}
    unsigned short* A = (unsigned short*)carve((size_t)NTOT * 128 * 2);
    // B: aggregate output; ALSO overlaid by bucket buffer during CSR build (9.6MB < 38.4MB)
    unsigned short* B = (unsigned short*)carve((size_t)NTOT * 128 * 2);
    int* rp    = (int*)carve((size_t)(NTOT + 1) * 4);
    int* bcnt  = (int*)carve((size_t)NBUCK * 4);
    int* bbase = (int*)carve((size_t)NBUCK * 4);
    int* csr   = (int*)carve((size_t)(2 * NEDGE) * 4);
    unsigned short* wtAll = (unsigned short*)carve((size_t)4 * 128 * PADW * 2);
    unsigned short* Wt1_rates = wtAll;
    unsigned short* Wt1_rev   = wtAll + 1 * (size_t)128 * PADW;
    unsigned short* Wt2_rates = wtAll + 2 * (size_t)128 * PADW;
    unsigned short* Wt2_rev   = wtAll + 3 * (size_t)128 * PADW;

    unsigned int* bbuf = (unsigned int*)B;        // overlay: consumed before aggregate writes B

    unsigned short* xu_bf = A;
    unsigned short* xi_bf = A + (size_t)NUSER * 128;
    unsigned short* h_item = A;
    unsigned short* h_user = A + (size_t)NITEM * 128;
    unsigned short* agg_item = B;
    unsigned short* agg_user = B + (size_t)NITEM * 128;

    // --- CSR build (LDS-staged bucketed counting sort) ---
    hipMemsetAsync(bcnt, 0, (size_t)NBUCK * 4, stream);
    bin_edges<<<NBINB, 256, 0, stream>>>(src_rates, dst_rates, src_rev, dst_rev, bcnt, bbuf);
    bscan<<<1, 256, 0, stream>>>(bcnt, bbase);
    build_csr<<<NBUCK, 256, 0, stream>>>(bcnt, bbase, bbuf, rp, csr);

    // --- prep: weights + feature bf16 ---
    wprep<<<4, 256, 0, stream>>>(W1_rates, W1_rev, W2_rates, W2_rev, wtAll);
    cvt_bf<<<2048, 256, 0, stream>>>(x_user, x_item, A);

    int nbI = (NITEM + 63) / 64, nbU = (NUSER + 63) / 64;
    int nbAgg = (NTOT + 7) / 8;

    // --- layer 1 ---
    aggregate_bf<<<nbAgg, 256, 0, stream>>>(xu_bf, xi_bf, rp, csr, B);
    gemm_mfma<<<nbI, 256, 0, stream>>>(agg_item, Wt1_rates, b1_rates, nullptr, h_item, NITEM, 1);
    gemm_mfma<<<nbU, 256, 0, stream>>>(agg_user, Wt1_rev,   b1_rev,   nullptr, h_user, NUSER, 1);

    // --- layer 2 ---
    aggregate_bf<<<nbAgg, 256, 0, stream>>>(h_user, h_item, rp, csr, B);
    gemm_mfma<<<nbI, 256, 0, stream>>>(agg_item, Wt2_rates, b2_rates, o_item, nullptr, NITEM, 0);
    gemm_mfma<<<nbU, 256, 0, stream>>>(agg_user, Wt2_rev,   b2_rev,   o_user, nullptr, NUSER, 0);
}

// Round 9
// 274.435 us; speedup vs baseline: 1.5670x; 1.0209x over previous
//
#include <hip/hip_runtime.h>
#include <cstdint>
#include <cstddef>

#define NUSER 100000
#define NITEM 50000
#define NTOT  150000          // NITEM + NUSER (item rows first, then user rows)
#define NEDGE 500000
#define NEG_SLOPE 0.01f
#define PADW 136              // 128 + 8 bf16 pad (16B) -> conflict-free ds_read_b128

// ---- bucketed CSR build params ----
// Item rows: mean degree 10 (500k/50k); 512 rows * 10 = 5120 mean, sigma ~71 -> GCAP 8192 = +43 sigma.
#define BROWS 512                                  // rows per bucket
#define BSHIFT 9
#define NBUCK ((NTOT + BROWS - 1) / BROWS)         // 293
#define GCAP  8192                                 // global cap per bucket
#define EPB   2048                                 // edges per bin block (245 blocks -> ~1/CU)
#define NBINB ((NEDGE + EPB - 1) / EPB)            // 245
#define NENT  (2 * EPB)                            // 4096 entries per bin block

typedef __attribute__((ext_vector_type(8))) short bf16x8;
typedef __attribute__((ext_vector_type(4))) float f32x4;

__device__ __forceinline__ unsigned short f2bf(float f) {
    unsigned int u = __builtin_bit_cast(unsigned int, f);
    unsigned int r = u + 0x7fffu + ((u >> 16) & 1u);   // RNE
    return (unsigned short)(r >> 16);
}
__device__ __forceinline__ float bf2f(unsigned int b) {
    unsigned int u = (b & 0xffffu) << 16;
    return __builtin_bit_cast(float, u);
}
__device__ __forceinline__ unsigned int pack2(float lo, float hi) {
    return (unsigned int)f2bf(lo) | ((unsigned int)f2bf(hi) << 16);
}

// ---------------- CSR build phase 1: LDS-staged binning ----------------
// entry = (row & 511) << 17 | src    (src < 2^17, row_local < 2^9)

__global__ __launch_bounds__(256) void bin_edges(const int* __restrict__ src_rates, const int* __restrict__ dst_rates,
                                                 const int* __restrict__ src_rev,   const int* __restrict__ dst_rev,
                                                 int* __restrict__ bcnt, unsigned int* __restrict__ bbuf) {
    __shared__ int h[NBUCK];       // per-block bucket counts
    __shared__ int hs[NBUCK];      // staging segment start
    __shared__ int hbase[NBUCK];   // reserved global offset per bucket
    __shared__ int hcur[NBUCK];    // staging cursor
    __shared__ int bsc[256];
    __shared__ unsigned int stage[NENT];

    int t = threadIdx.x;
    int e0 = blockIdx.x * EPB;
    int n = NEDGE - e0; if (n > EPB) n = EPB;

    for (int i = t; i < NBUCK; i += 256) h[i] = 0;
    __syncthreads();

    // pass 1: count
    for (int i = t; i < n; i += 256) {
        int e = e0 + i;
        atomicAdd(&h[dst_rates[e] >> BSHIFT], 1);
        atomicAdd(&h[(NITEM + dst_rev[e]) >> BSHIFT], 1);
    }
    __syncthreads();

    // local exclusive scan over NBUCK (2 elements/thread) + reserve global segments
    int i0 = 2 * t, i1 = 2 * t + 1;
    int v0 = (i0 < NBUCK) ? h[i0] : 0;
    int v1 = (i1 < NBUCK) ? h[i1] : 0;
    int ls = v0 + v1;
    bsc[t] = ls;
    __syncthreads();
    for (int off = 1; off < 256; off <<= 1) {
        int x = (t >= off) ? bsc[t - off] : 0;
        __syncthreads();
        bsc[t] += x;
        __syncthreads();
    }
    int run = bsc[t] - ls;
    if (i0 < NBUCK) {
        hs[i0] = run; hcur[i0] = run;
        hbase[i0] = (v0 > 0) ? atomicAdd(&bcnt[i0], v0) : 0;
    }
    if (i1 < NBUCK) {
        hs[i1] = run + v0; hcur[i1] = run + v0;
        hbase[i1] = (v1 > 0) ? atomicAdd(&bcnt[i1], v1) : 0;
    }
    __syncthreads();

    // pass 2: scatter into LDS staging (bucket-sorted)
    for (int i = t; i < n; i += 256) {
        int e = e0 + i;
        int r1 = dst_rates[e];
        int p1 = atomicAdd(&hcur[r1 >> BSHIFT], 1);
        if (p1 < NENT)
            stage[p1] = ((unsigned)(r1 & (BROWS - 1)) << 17) | (unsigned)src_rates[e];
        int r2 = NITEM + dst_rev[e];
        int p2 = atomicAdd(&hcur[r2 >> BSHIFT], 1);
        if (p2 < NENT)
            stage[p2] = ((unsigned)(r2 & (BROWS - 1)) << 17) | (unsigned)src_rev[e];
    }
    __syncthreads();

    // flush: one wave per bucket (round-robin), contiguous coalesced writes
    int wid = t >> 6, lane = t & 63;
    for (int b = wid; b < NBUCK; b += 4) {
        int cnt = h[b];
        if (cnt > NENT) cnt = NENT;    // defensive clamp
        int gb = hbase[b];
        int sb = hs[b];
        for (int i = lane; i < cnt; i += 64) {
            int gpos = gb + i;
            if (gpos < GCAP) bbuf[(size_t)b * GCAP + gpos] = stage[sb + i];
        }
    }
}

// single block: exclusive scan of NBUCK bucket counts -> bbase (2 elements/thread)
__global__ __launch_bounds__(256) void bscan(const int* __restrict__ bcnt, int* __restrict__ bbase) {
    __shared__ int sm[256];
    int t = threadIdx.x;
    int i0 = 2 * t, i1 = 2 * t + 1;
    int v0 = (i0 < NBUCK) ? bcnt[i0] : 0;
    int v1 = (i1 < NBUCK) ? bcnt[i1] : 0;
    int ls = v0 + v1;
    sm[t] = ls;
    __syncthreads();
    for (int off = 1; off < 256; off <<= 1) {
        int x = (t >= off) ? sm[t - off] : 0;
        __syncthreads();
        sm[t] += x;
        __syncthreads();
    }
    int run = sm[t] - ls;
    if (i0 < NBUCK) bbase[i0] = run;
    if (i1 < NBUCK) bbase[i1] = run + v0;
}

// ---------------- CSR build phase 2: one block per bucket ----------------

__global__ __launch_bounds__(256) void build_csr(const int* __restrict__ bcnt, const int* __restrict__ bbase,
                                                 const unsigned int* __restrict__ bbuf,
                                                 int* __restrict__ rp, int* __restrict__ csr) {
    __shared__ unsigned int ent[GCAP];   // 32 KB
    __shared__ int h[BROWS], hs[BROWS];  // 4 KB
    __shared__ int bsc[256];

    int bk = blockIdx.x, t = threadIdx.x;
    int base = bbase[bk];
    int n = bcnt[bk];
    if (n > GCAP) n = GCAP;              // defensive (cannot trigger per capacity math)

    const unsigned int* src = bbuf + (size_t)bk * GCAP;
    for (int i = t; i < n; i += 256) ent[i] = src[i];
    h[t] = 0; h[t + 256] = 0;
    __syncthreads();

    for (int i = t; i < n; i += 256) atomicAdd(&h[ent[i] >> 17], 1);
    __syncthreads();

    int v0 = h[2 * t], v1 = h[2 * t + 1];
    int ls = v0 + v1;
    bsc[t] = ls;
    __syncthreads();
    for (int off = 1; off < 256; off <<= 1) {
        int x = (t >= off) ? bsc[t - off] : 0;
        __syncthreads();
        bsc[t] += x;
        __syncthreads();
    }
    int run = bsc[t] - ls;
    hs[2 * t] = run;
    hs[2 * t + 1] = run + v0;
    __syncthreads();

    for (int r = t; r < BROWS; r += 256) {
        int row = bk * BROWS + r;
        if (row < NTOT) rp[row] = base + hs[r];
        h[r] = 0;
    }
    if (bk == 0 && t == 0) rp[NTOT] = 2 * NEDGE;
    __syncthreads();

    for (int i = t; i < n; i += 256) {
        unsigned int ev = ent[i];
        int rl = (int)(ev >> 17);
        int pos = base + hs[rl] + atomicAdd(&h[rl], 1);
        csr[pos] = (int)(ev & 0x1FFFFu);
    }
}

// ---------------- weight prep: W[128][128] fp32 -> Wt bf16 [col][k] padded PADW ----------------

__global__ void wprep(const float* __restrict__ w0, const float* __restrict__ w1,
                      const float* __restrict__ w2, const float* __restrict__ w3,
                      unsigned short* __restrict__ wt) {
    const float* src = (blockIdx.x == 0) ? w0 : (blockIdx.x == 1) ? w1 : (blockIdx.x == 2) ? w2 : w3;
    unsigned short* dst = wt + (size_t)blockIdx.x * 128 * PADW;
    for (int i = threadIdx.x; i < 16384; i += 256) {
        int k = i >> 7, c = i & 127;
        dst[c * PADW + k] = f2bf(src[i]);
    }
}

// ---------------- x -> bf16 convert ----------------

__global__ void cvt_bf(const float* __restrict__ xu, const float* __restrict__ xi,
                       unsigned short* __restrict__ dst) {
    const int n8u = NUSER * 128 / 8;
    const int n8  = (NUSER + NITEM) * 128 / 8;
    for (int i = blockIdx.x * blockDim.x + threadIdx.x; i < n8; i += gridDim.x * blockDim.x) {
        const float* s = (i < n8u) ? (xu + (size_t)i * 8) : (xi + (size_t)(i - n8u) * 8);
        float4 a = ((const float4*)s)[0];
        float4 b = ((const float4*)s)[1];
        uint4 o;
        o.x = pack2(a.x, a.y);
        o.y = pack2(a.z, a.w);
        o.z = pack2(b.x, b.y);
        o.w = pack2(b.z, b.w);
        ((uint4*)dst)[i] = o;
    }
}

// ---------------- aggregation (bf16 in -> bf16 out), both relations in one grid ----------------

__global__ __launch_bounds__(256) void aggregate_bf(const unsigned short* __restrict__ featA,  // item rows
                                                    const unsigned short* __restrict__ featB,  // user rows
                                                    const int* __restrict__ rp, const int* __restrict__ csr,
                                                    unsigned short* __restrict__ outb) {
    int row = blockIdx.x * 8 + (threadIdx.x >> 5);
    if (row >= NTOT) return;
    const unsigned short* feat = (row < NITEM) ? featA : featB;
    int l = threadIdx.x & 31;
    int sub = l >> 4, l16 = l & 15;
    int b = rp[row], e = rp[row + 1];
    float a0 = 0.f, a1 = 0.f, a2 = 0.f, a3 = 0.f, a4 = 0.f, a5 = 0.f, a6 = 0.f, a7 = 0.f;
    for (int j = b + sub; j < e; j += 2) {
        int s = csr[j];
        uint4 v = *((const uint4*)(feat + (size_t)s * 128) + l16);
        a0 += bf2f(v.x); a1 += bf2f(v.x >> 16);
        a2 += bf2f(v.y); a3 += bf2f(v.y >> 16);
        a4 += bf2f(v.z); a5 += bf2f(v.z >> 16);
        a6 += bf2f(v.w); a7 += bf2f(v.w >> 16);
    }
    a0 += __shfl_xor(a0, 16); a1 += __shfl_xor(a1, 16);
    a2 += __shfl_xor(a2, 16); a3 += __shfl_xor(a3, 16);
    a4 += __shfl_xor(a4, 16); a5 += __shfl_xor(a5, 16);
    a6 += __shfl_xor(a6, 16); a7 += __shfl_xor(a7, 16);
    if (sub == 0) {
        int deg = e - b;
        float inv = 1.0f / (float)(deg > 0 ? deg : 1);
        uint4 o;
        o.x = pack2(a0 * inv, a1 * inv);
        o.y = pack2(a2 * inv, a3 * inv);
        o.z = pack2(a4 * inv, a5 * inv);
        o.w = pack2(a6 * inv, a7 * inv);
        *((uint4*)(outb + (size_t)row * 128) + l16) = o;
    }
}

// ---------------- MFMA GEMM: out[N][128] = bf16 in[N][128] @ W + bias (+leaky) ----------------

__global__ __launch_bounds__(256) void gemm_mfma(const unsigned short* __restrict__ in,
                                                 const unsigned short* __restrict__ wt,
                                                 const float* __restrict__ bias,
                                                 float* __restrict__ outF,             // fp32 path if non-null
                                                 unsigned short* __restrict__ outB,    // bf16 path otherwise
                                                 int N, int leaky) {
    __shared__ __attribute__((aligned(16))) unsigned short wl[128 * PADW];
    __shared__ __attribute__((aligned(16))) unsigned short xl[64 * PADW];
    int t = threadIdx.x;
    int row0 = blockIdx.x * 64;

    for (int i = t; i < 128 * PADW / 8; i += 256)
        ((uint4*)wl)[i] = ((const uint4*)wt)[i];

    for (int i = t; i < 1024; i += 256) {
        int r = i >> 4, c = i & 15;
        int row = row0 + r;
        uint4 v = make_uint4(0u, 0u, 0u, 0u);
        if (row < N) v = ((const uint4*)(in + (size_t)row * 128))[c];
        ((uint4*)xl)[r * (PADW / 8) + c] = v;
    }
    __syncthreads();

    int lane = t & 63, w = t >> 6;
    int l16 = lane & 15, kq = lane >> 4;
    int rowb = w * 16;

    f32x4 acc[8];
    #pragma unroll
    for (int i = 0; i < 8; ++i) acc[i] = (f32x4){0.f, 0.f, 0.f, 0.f};

    #pragma unroll
    for (int ks = 0; ks < 4; ++ks) {
        int ko = ks * 32 + kq * 8;
        bf16x8 af = *(const bf16x8*)&xl[(rowb + l16) * PADW + ko];
        #pragma unroll
        for (int t8 = 0; t8 < 8; ++t8) {
            bf16x8 bf = *(const bf16x8*)&wl[(t8 * 16 + l16) * PADW + ko];
            acc[t8] = __builtin_amdgcn_mfma_f32_16x16x32_bf16(af, bf, acc[t8], 0, 0, 0);
        }
    }

    float bv[8];
    #pragma unroll
    for (int t8 = 0; t8 < 8; ++t8) bv[t8] = bias[t8 * 16 + l16];

    if (outF) {
        #pragma unroll
        for (int t8 = 0; t8 < 8; ++t8) {
            #pragma unroll
            for (int j = 0; j < 4; ++j) {
                int row = row0 + rowb + kq * 4 + j;
                if (row < N) {
                    float v = acc[t8][j] + bv[t8];
                    if (leaky) v = v > 0.f ? v : NEG_SLOPE * v;
                    outF[(size_t)row * 128 + t8 * 16 + l16] = v;
                }
            }
        }
    } else {
        #pragma unroll
        for (int t8 = 0; t8 < 8; ++t8) {
            #pragma unroll
            for (int j = 0; j < 4; ++j) {
                float v = acc[t8][j] + bv[t8];
                if (leaky) v = v > 0.f ? v : NEG_SLOPE * v;
                xl[(rowb + kq * 4 + j) * PADW + t8 * 16 + l16] = f2bf(v);
            }
        }
        __syncthreads();
        for (int i = t; i < 1024; i += 256) {
            int r = i >> 4, c = i & 15;
            int row = row0 + r;
            if (row < N)
                ((uint4*)(outB + (size_t)row * 128))[c] = ((uint4*)xl)[r * (PADW / 8) + c];
        }
    }
}

// ---------------- launch ----------------

extern "C" void kernel_launch(void* const* d_in, const int* in_sizes, int n_in,
                              void* d_out, int out_size, void* d_ws, size_t ws_size,
                              hipStream_t stream) {
    const float* x_user    = (const float*)d_in[0];
    const float* x_item    = (const float*)d_in[1];
    const int*   src_rates = (const int*)d_in[2];
    const int*   dst_rates = (const int*)d_in[3];
    const int*   src_rev   = (const int*)d_in[4];
    const int*   dst_rev   = (const int*)d_in[5];
    const float* W1_rates  = (const float*)d_in[6];
    const float* b1_rates  = (const float*)d_in[7];
    const float* W1_rev    = (const float*)d_in[8];
    const float* b1_rev    = (const float*)d_in[9];
    const float* W2_rates  = (const float*)d_in[10];
    const float* b2_rates  = (const float*)d_in[11];
    const float* W2_rev    = (const float*)d_in[12];
    const float* b2_rev    = (const float*)d_in[13];

    float* out    = (float*)d_out;
    float* o_user = out;                          // [NUSER,128] fp32
    float* o_item = out + (size_t)NUSER * 128;    // [NITEM,128] fp32

    char* ws = (char*)d_ws;
    size_t off = 0;
    auto carve = [&](size_t bytes) -> void* {
        void* p = ws + off;
        off = (off + bytes + 255) & ~(size_t)255;
        return p;
    };
    // A: first x_bf {xu[NU],xi[NI]}, later h {h_item[NI], h_user[NU]}
    unsigned short* A = (unsigned short*)carve((size_t)NTOT * 128 * 2);
    // B: aggregate output; overlaid by bucket buffer during CSR build (9.6MB < 38.4MB)
    unsigned short* B = (unsigned short*)carve((size_t)NTOT * 128 * 2);
    int* rp    = (int*)carve((size_t)(NTOT + 1) * 4);
    int* bcnt  = (int*)carve((size_t)NBUCK * 4);
    int* bbase = (int*)carve((size_t)NBUCK * 4);
    int* csr   = (int*)carve((size_t)(2 * NEDGE) * 4);
    unsigned short* wtAll = (unsigned short*)carve((size_t)4 * 128 * PADW * 2);
    unsigned short* Wt1_rates = wtAll;
    unsigned short* Wt1_rev   = wtAll + 1 * (size_t)128 * PADW;
    unsigned short* Wt2_rates = wtAll + 2 * (size_t)128 * PADW;
    unsigned short* Wt2_rev   = wtAll + 3 * (size_t)128 * PADW;

    unsigned int* bbuf = (unsigned int*)B;        // overlay: consumed before aggregate writes B

    unsigned short* xu_bf = A;
    unsigned short* xi_bf = A + (size_t)NUSER * 128;
    unsigned short* h_item = A;
    unsigned short* h_user = A + (size_t)NITEM * 128;
    unsigned short* agg_item = B;
    unsigned short* agg_user = B + (size_t)NITEM * 128;

    // --- CSR build (LDS-staged bucketed counting sort) ---
    hipMemsetAsync(bcnt, 0, (size_t)NBUCK * 4, stream);
    bin_edges<<<NBINB, 256, 0, stream>>>(src_rates, dst_rates, src_rev, dst_rev, bcnt, bbuf);
    bscan<<<1, 256, 0, stream>>>(bcnt, bbase);
    build_csr<<<NBUCK, 256, 0, stream>>>(bcnt, bbase, bbuf, rp, csr);

    // --- prep: weights + feature bf16 ---
    wprep<<<4, 256, 0, stream>>>(W1_rates, W1_rev, W2_rates, W2_rev, wtAll);
    cvt_bf<<<2048, 256, 0, stream>>>(x_user, x_item, A);

    int nbI = (NITEM + 63) / 64, nbU = (NUSER + 63) / 64;
    int nbAgg = (NTOT + 7) / 8;

    // --- layer 1 ---
    aggregate_bf<<<nbAgg, 256, 0, stream>>>(xu_bf, xi_bf, rp, csr, B);
    gemm_mfma<<<nbI, 256, 0, stream>>>(agg_item, Wt1_rates, b1_rates, nullptr, h_item, NITEM, 1);
    gemm_mfma<<<nbU, 256, 0, stream>>>(agg_user, Wt1_rev,   b1_rev,   nullptr, h_user, NUSER, 1);

    // --- layer 2 ---
    aggregate_bf<<<nbAgg, 256, 0, stream>>>(h_user, h_item, rp, csr, B);
    gemm_mfma<<<nbI, 256, 0, stream>>>(agg_item, Wt2_rates, b2_rates, o_item, nullptr, NITEM, 0);
    gemm_mfma<<<nbU, 256, 0, stream>>>(agg_user, Wt2_rev,   b2_rev,   o_user, nullptr, NUSER, 0);
}

// Round 10
// 239.293 us; speedup vs baseline: 1.7971x; 1.1469x over previous
//
#include <hip/hip_runtime.h>
#include <cstdint>
#include <cstddef>

#define NUSER 100000
#define NITEM 50000
#define NTOT  150000          // NITEM + NUSER (item rows first, then user rows)
#define NEDGE 500000
#define NEG_SLOPE 0.01f
#define PADW 136              // 128 + 8 bf16 pad (16B) -> conflict-free ds_read_b128

// ---- bucketed CSR build params ----
// Item rows: mean degree 10 (500k/50k); 512 rows * 10 = 5120 mean, sigma ~71 -> GCAP 8192 = +43 sigma.
#define BROWS 512                                  // rows per bucket
#define BSHIFT 9
#define NBUCK ((NTOT + BROWS - 1) / BROWS)         // 293
#define GCAP  8192                                 // global cap per bucket
#define EPB   2048                                 // edges per bin block (245 blocks -> ~1/CU)
#define NBINB ((NEDGE + EPB - 1) / EPB)            // 245
#define NENT  (2 * EPB)                            // 4096 entries per bin block

typedef __attribute__((ext_vector_type(8))) short bf16x8;
typedef __attribute__((ext_vector_type(4))) float f32x4;

__device__ __forceinline__ unsigned short f2bf(float f) {
    unsigned int u = __builtin_bit_cast(unsigned int, f);
    unsigned int r = u + 0x7fffu + ((u >> 16) & 1u);   // RNE
    return (unsigned short)(r >> 16);
}
__device__ __forceinline__ float bf2f(unsigned int b) {
    unsigned int u = (b & 0xffffu) << 16;
    return __builtin_bit_cast(float, u);
}
__device__ __forceinline__ unsigned int pack2(float lo, float hi) {
    return (unsigned int)f2bf(lo) | ((unsigned int)f2bf(hi) << 16);
}

// ---------------- CSR build phase 1: LDS-staged binning ----------------
// entry = (row & 511) << 17 | src    (src < 2^17, row_local < 2^9)

__global__ __launch_bounds__(256) void bin_edges(const int* __restrict__ src_rates, const int* __restrict__ dst_rates,
                                                 const int* __restrict__ src_rev,   const int* __restrict__ dst_rev,
                                                 int* __restrict__ bcnt, unsigned int* __restrict__ bbuf) {
    __shared__ int h[NBUCK];       // per-block bucket counts
    __shared__ int hs[NBUCK];      // staging segment start
    __shared__ int hbase[NBUCK];   // reserved global offset per bucket
    __shared__ int hcur[NBUCK];    // staging cursor
    __shared__ int bsc[256];
    __shared__ unsigned int stage[NENT];

    int t = threadIdx.x;
    int e0 = blockIdx.x * EPB;
    int n = NEDGE - e0; if (n > EPB) n = EPB;

    for (int i = t; i < NBUCK; i += 256) h[i] = 0;
    __syncthreads();

    // pass 1: count
    for (int i = t; i < n; i += 256) {
        int e = e0 + i;
        atomicAdd(&h[dst_rates[e] >> BSHIFT], 1);
        atomicAdd(&h[(NITEM + dst_rev[e]) >> BSHIFT], 1);
    }
    __syncthreads();

    // local exclusive scan over NBUCK (2 elements/thread) + reserve global segments
    int i0 = 2 * t, i1 = 2 * t + 1;
    int v0 = (i0 < NBUCK) ? h[i0] : 0;
    int v1 = (i1 < NBUCK) ? h[i1] : 0;
    int ls = v0 + v1;
    bsc[t] = ls;
    __syncthreads();
    for (int off = 1; off < 256; off <<= 1) {
        int x = (t >= off) ? bsc[t - off] : 0;
        __syncthreads();
        bsc[t] += x;
        __syncthreads();
    }
    int run = bsc[t] - ls;
    if (i0 < NBUCK) {
        hs[i0] = run; hcur[i0] = run;
        hbase[i0] = (v0 > 0) ? atomicAdd(&bcnt[i0], v0) : 0;
    }
    if (i1 < NBUCK) {
        hs[i1] = run + v0; hcur[i1] = run + v0;
        hbase[i1] = (v1 > 0) ? atomicAdd(&bcnt[i1], v1) : 0;
    }
    __syncthreads();

    // pass 2: scatter into LDS staging (bucket-sorted)
    for (int i = t; i < n; i += 256) {
        int e = e0 + i;
        int r1 = dst_rates[e];
        int p1 = atomicAdd(&hcur[r1 >> BSHIFT], 1);
        if (p1 < NENT)
            stage[p1] = ((unsigned)(r1 & (BROWS - 1)) << 17) | (unsigned)src_rates[e];
        int r2 = NITEM + dst_rev[e];
        int p2 = atomicAdd(&hcur[r2 >> BSHIFT], 1);
        if (p2 < NENT)
            stage[p2] = ((unsigned)(r2 & (BROWS - 1)) << 17) | (unsigned)src_rev[e];
    }
    __syncthreads();

    // flush: one wave per bucket (round-robin), contiguous coalesced writes
    int wid = t >> 6, lane = t & 63;
    for (int b = wid; b < NBUCK; b += 4) {
        int cnt = h[b];
        if (cnt > NENT) cnt = NENT;    // defensive clamp
        int gb = hbase[b];
        int sb = hs[b];
        for (int i = lane; i < cnt; i += 64) {
            int gpos = gb + i;
            if (gpos < GCAP) bbuf[(size_t)b * GCAP + gpos] = stage[sb + i];
        }
    }
}

// single block: exclusive scan of NBUCK bucket counts -> bbase (2 elements/thread)
__global__ __launch_bounds__(256) void bscan(const int* __restrict__ bcnt, int* __restrict__ bbase) {
    __shared__ int sm[256];
    int t = threadIdx.x;
    int i0 = 2 * t, i1 = 2 * t + 1;
    int v0 = (i0 < NBUCK) ? bcnt[i0] : 0;
    int v1 = (i1 < NBUCK) ? bcnt[i1] : 0;
    int ls = v0 + v1;
    sm[t] = ls;
    __syncthreads();
    for (int off = 1; off < 256; off <<= 1) {
        int x = (t >= off) ? sm[t - off] : 0;
        __syncthreads();
        sm[t] += x;
        __syncthreads();
    }
    int run = sm[t] - ls;
    if (i0 < NBUCK) bbase[i0] = run;
    if (i1 < NBUCK) bbase[i1] = run + v0;
}

// ---------------- CSR build phase 2: one block per bucket ----------------

__global__ __launch_bounds__(256) void build_csr(const int* __restrict__ bcnt, const int* __restrict__ bbase,
                                                 const unsigned int* __restrict__ bbuf,
                                                 int* __restrict__ rp, int* __restrict__ csr) {
    __shared__ unsigned int ent[GCAP];   // 32 KB
    __shared__ int h[BROWS], hs[BROWS];  // 4 KB
    __shared__ int bsc[256];

    int bk = blockIdx.x, t = threadIdx.x;
    int base = bbase[bk];
    int n = bcnt[bk];
    if (n > GCAP) n = GCAP;              // defensive (cannot trigger per capacity math)

    const unsigned int* src = bbuf + (size_t)bk * GCAP;
    for (int i = t; i < n; i += 256) ent[i] = src[i];
    h[t] = 0; h[t + 256] = 0;
    __syncthreads();

    for (int i = t; i < n; i += 256) atomicAdd(&h[ent[i] >> 17], 1);
    __syncthreads();

    int v0 = h[2 * t], v1 = h[2 * t + 1];
    int ls = v0 + v1;
    bsc[t] = ls;
    __syncthreads();
    for (int off = 1; off < 256; off <<= 1) {
        int x = (t >= off) ? bsc[t - off] : 0;
        __syncthreads();
        bsc[t] += x;
        __syncthreads();
    }
    int run = bsc[t] - ls;
    hs[2 * t] = run;
    hs[2 * t + 1] = run + v0;
    __syncthreads();

    for (int r = t; r < BROWS; r += 256) {
        int row = bk * BROWS + r;
        if (row < NTOT) rp[row] = base + hs[r];
        h[r] = 0;
    }
    if (bk == 0 && t == 0) rp[NTOT] = 2 * NEDGE;
    __syncthreads();

    for (int i = t; i < n; i += 256) {
        unsigned int ev = ent[i];
        int rl = (int)(ev >> 17);
        int pos = base + hs[rl] + atomicAdd(&h[rl], 1);
        csr[pos] = (int)(ev & 0x1FFFFu);
    }
}

// ---------------- weight prep: W[128][128] fp32 -> Wt bf16 [col][k] padded PADW ----------------

__global__ void wprep(const float* __restrict__ w0, const float* __restrict__ w1,
                      const float* __restrict__ w2, const float* __restrict__ w3,
                      unsigned short* __restrict__ wt) {
    const float* src = (blockIdx.x == 0) ? w0 : (blockIdx.x == 1) ? w1 : (blockIdx.x == 2) ? w2 : w3;
    unsigned short* dst = wt + (size_t)blockIdx.x * 128 * PADW;
    for (int i = threadIdx.x; i < 16384; i += 256) {
        int k = i >> 7, c = i & 127;
        dst[c * PADW + k] = f2bf(src[i]);
    }
}

// ---------------- x -> bf16 convert ----------------

__global__ void cvt_bf(const float* __restrict__ xu, const float* __restrict__ xi,
                       unsigned short* __restrict__ dst) {
    const int n8u = NUSER * 128 / 8;
    const int n8  = (NUSER + NITEM) * 128 / 8;
    for (int i = blockIdx.x * blockDim.x + threadIdx.x; i < n8; i += gridDim.x * blockDim.x) {
        const float* s = (i < n8u) ? (xu + (size_t)i * 8) : (xi + (size_t)(i - n8u) * 8);
        float4 a = ((const float4*)s)[0];
        float4 b = ((const float4*)s)[1];
        uint4 o;
        o.x = pack2(a.x, a.y);
        o.y = pack2(a.z, a.w);
        o.z = pack2(b.x, b.y);
        o.w = pack2(b.z, b.w);
        ((uint4*)dst)[i] = o;
    }
}

// ---------------- aggregation (bf16 in -> bf16 out), both relations, 2x-unrolled gather ----------------

__global__ __launch_bounds__(256) void aggregate_bf(const unsigned short* __restrict__ featA,  // item rows
                                                    const unsigned short* __restrict__ featB,  // user rows
                                                    const int* __restrict__ rp, const int* __restrict__ csr,
                                                    unsigned short* __restrict__ outb) {
    int row = blockIdx.x * 8 + (threadIdx.x >> 5);
    if (row >= NTOT) return;
    const unsigned short* feat = (row < NITEM) ? featA : featB;
    int l = threadIdx.x & 31;
    int sub = l >> 4, l16 = l & 15;
    int b = rp[row], e = rp[row + 1];
    float a0 = 0.f, a1 = 0.f, a2 = 0.f, a3 = 0.f, a4 = 0.f, a5 = 0.f, a6 = 0.f, a7 = 0.f;
    int j = b + sub;
    // 2 independent gathers in flight per half-wave sub (4 edges/row total in flight)
    for (; j + 2 < e; j += 4) {
        int s0 = csr[j];
        int s1 = csr[j + 2];
        uint4 v0 = *((const uint4*)(feat + (size_t)s0 * 128) + l16);
        uint4 v1 = *((const uint4*)(feat + (size_t)s1 * 128) + l16);
        a0 += bf2f(v0.x); a1 += bf2f(v0.x >> 16);
        a2 += bf2f(v0.y); a3 += bf2f(v0.y >> 16);
        a4 += bf2f(v0.z); a5 += bf2f(v0.z >> 16);
        a6 += bf2f(v0.w); a7 += bf2f(v0.w >> 16);
        a0 += bf2f(v1.x); a1 += bf2f(v1.x >> 16);
        a2 += bf2f(v1.y); a3 += bf2f(v1.y >> 16);
        a4 += bf2f(v1.z); a5 += bf2f(v1.z >> 16);
        a6 += bf2f(v1.w); a7 += bf2f(v1.w >> 16);
    }
    if (j < e) {
        int s0 = csr[j];
        uint4 v0 = *((const uint4*)(feat + (size_t)s0 * 128) + l16);
        a0 += bf2f(v0.x); a1 += bf2f(v0.x >> 16);
        a2 += bf2f(v0.y); a3 += bf2f(v0.y >> 16);
        a4 += bf2f(v0.z); a5 += bf2f(v0.z >> 16);
        a6 += bf2f(v0.w); a7 += bf2f(v0.w >> 16);
    }
    a0 += __shfl_xor(a0, 16); a1 += __shfl_xor(a1, 16);
    a2 += __shfl_xor(a2, 16); a3 += __shfl_xor(a3, 16);
    a4 += __shfl_xor(a4, 16); a5 += __shfl_xor(a5, 16);
    a6 += __shfl_xor(a6, 16); a7 += __shfl_xor(a7, 16);
    if (sub == 0) {
        int deg = e - b;
        float inv = 1.0f / (float)(deg > 0 ? deg : 1);
        uint4 o;
        o.x = pack2(a0 * inv, a1 * inv);
        o.y = pack2(a2 * inv, a3 * inv);
        o.z = pack2(a4 * inv, a5 * inv);
        o.w = pack2(a6 * inv, a7 * inv);
        *((uint4*)(outb + (size_t)row * 128) + l16) = o;
    }
}

// ---------------- MFMA GEMM, both regions in one launch ----------------
// blocks [0, nbI) -> item rows, weights wtI/bI; blocks [nbI, nbI+nbU) -> user rows, wtU/bU.
// fp32 path (outFI/outFU non-null) or bf16 path (outB, global-row indexed).

__global__ __launch_bounds__(256) void gemm_both(const unsigned short* __restrict__ in,
                                                 const unsigned short* __restrict__ wtI,
                                                 const unsigned short* __restrict__ wtU,
                                                 const float* __restrict__ bI,
                                                 const float* __restrict__ bU,
                                                 float* __restrict__ outFI, float* __restrict__ outFU,
                                                 unsigned short* __restrict__ outB,
                                                 int nbI, int leaky) {
    __shared__ __attribute__((aligned(16))) unsigned short wl[128 * PADW];
    __shared__ __attribute__((aligned(16))) unsigned short xl[64 * PADW];
    int t = threadIdx.x;
    int bi = blockIdx.x;
    bool item = bi < nbI;
    int row0 = item ? bi * 64 : NITEM + (bi - nbI) * 64;
    int Nend = item ? NITEM : NTOT;
    const unsigned short* wt = item ? wtI : wtU;
    const float* bias = item ? bI : bU;

    for (int i = t; i < 128 * PADW / 8; i += 256)
        ((uint4*)wl)[i] = ((const uint4*)wt)[i];

    for (int i = t; i < 1024; i += 256) {
        int r = i >> 4, c = i & 15;
        int row = row0 + r;
        uint4 v = make_uint4(0u, 0u, 0u, 0u);
        if (row < Nend) v = ((const uint4*)(in + (size_t)row * 128))[c];
        ((uint4*)xl)[r * (PADW / 8) + c] = v;
    }
    __syncthreads();

    int lane = t & 63, w = t >> 6;
    int l16 = lane & 15, kq = lane >> 4;
    int rowb = w * 16;

    f32x4 acc[8];
    #pragma unroll
    for (int i = 0; i < 8; ++i) acc[i] = (f32x4){0.f, 0.f, 0.f, 0.f};

    #pragma unroll
    for (int ks = 0; ks < 4; ++ks) {
        int ko = ks * 32 + kq * 8;
        bf16x8 af = *(const bf16x8*)&xl[(rowb + l16) * PADW + ko];
        #pragma unroll
        for (int t8 = 0; t8 < 8; ++t8) {
            bf16x8 bf = *(const bf16x8*)&wl[(t8 * 16 + l16) * PADW + ko];
            acc[t8] = __builtin_amdgcn_mfma_f32_16x16x32_bf16(af, bf, acc[t8], 0, 0, 0);
        }
    }

    float bv[8];
    #pragma unroll
    for (int t8 = 0; t8 < 8; ++t8) bv[t8] = bias[t8 * 16 + l16];

    if (outB == nullptr) {
        float* o = item ? outFI : outFU;
        int rbase = item ? 0 : NITEM;          // fp32 outputs are region-local row indexed
        #pragma unroll
        for (int t8 = 0; t8 < 8; ++t8) {
            #pragma unroll
            for (int j = 0; j < 4; ++j) {
                int row = row0 + rowb + kq * 4 + j;
                if (row < Nend) {
                    float v = acc[t8][j] + bv[t8];
                    if (leaky) v = v > 0.f ? v : NEG_SLOPE * v;
                    o[(size_t)(row - rbase) * 128 + t8 * 16 + l16] = v;
                }
            }
        }
    } else {
        #pragma unroll
        for (int t8 = 0; t8 < 8; ++t8) {
            #pragma unroll
            for (int j = 0; j < 4; ++j) {
                float v = acc[t8][j] + bv[t8];
                if (leaky) v = v > 0.f ? v : NEG_SLOPE * v;
                xl[(rowb + kq * 4 + j) * PADW + t8 * 16 + l16] = f2bf(v);
            }
        }
        __syncthreads();
        for (int i = t; i < 1024; i += 256) {
            int r = i >> 4, c = i & 15;
            int row = row0 + r;
            if (row < Nend)
                ((uint4*)(outB + (size_t)row * 128))[c] = ((uint4*)xl)[r * (PADW / 8) + c];
        }
    }
}

// ---------------- launch ----------------

extern "C" void kernel_launch(void* const* d_in, const int* in_sizes, int n_in,
                              void* d_out, int out_size, void* d_ws, size_t ws_size,
                              hipStream_t stream) {
    const float* x_user    = (const float*)d_in[0];
    const float* x_item    = (const float*)d_in[1];
    const int*   src_rates = (const int*)d_in[2];
    const int*   dst_rates = (const int*)d_in[3];
    const int*   src_rev   = (const int*)d_in[4];
    const int*   dst_rev   = (const int*)d_in[5];
    const float* W1_rates  = (const float*)d_in[6];
    const float* b1_rates  = (const float*)d_in[7];
    const float* W1_rev    = (const float*)d_in[8];
    const float* b1_rev    = (const float*)d_in[9];
    const float* W2_rates  = (const float*)d_in[10];
    const float* b2_rates  = (const float*)d_in[11];
    const float* W2_rev    = (const float*)d_in[12];
    const float* b2_rev    = (const float*)d_in[13];

    float* out    = (float*)d_out;
    float* o_user = out;                          // [NUSER,128] fp32
    float* o_item = out + (size_t)NUSER * 128;    // [NITEM,128] fp32

    char* ws = (char*)d_ws;
    size_t off = 0;
    auto carve = [&](size_t bytes) -> void* {
        void* p = ws + off;
        off = (off + bytes + 255) & ~(size_t)255;
        return p;
    };
    // A: first x_bf {xu[NU],xi[NI]}, later h {h_item[NI], h_user[NU]} (global-row indexed)
    unsigned short* A = (unsigned short*)carve((size_t)NTOT * 128 * 2);
    // B: aggregate output; overlaid by bucket buffer during CSR build (9.6MB < 38.4MB)
    unsigned short* B = (unsigned short*)carve((size_t)NTOT * 128 * 2);
    int* rp    = (int*)carve((size_t)(NTOT + 1) * 4);
    int* bcnt  = (int*)carve((size_t)NBUCK * 4);
    int* bbase = (int*)carve((size_t)NBUCK * 4);
    int* csr   = (int*)carve((size_t)(2 * NEDGE) * 4);
    unsigned short* wtAll = (unsigned short*)carve((size_t)4 * 128 * PADW * 2);
    unsigned short* Wt1_rates = wtAll;
    unsigned short* Wt1_rev   = wtAll + 1 * (size_t)128 * PADW;
    unsigned short* Wt2_rates = wtAll + 2 * (size_t)128 * PADW;
    unsigned short* Wt2_rev   = wtAll + 3 * (size_t)128 * PADW;

    unsigned int* bbuf = (unsigned int*)B;        // overlay: consumed before aggregate writes B

    unsigned short* xu_bf = A;
    unsigned short* xi_bf = A + (size_t)NUSER * 128;
    unsigned short* h_item = A;
    unsigned short* h_user = A + (size_t)NITEM * 128;

    // --- CSR build (LDS-staged bucketed counting sort) ---
    hipMemsetAsync(bcnt, 0, (size_t)NBUCK * 4, stream);
    bin_edges<<<NBINB, 256, 0, stream>>>(src_rates, dst_rates, src_rev, dst_rev, bcnt, bbuf);
    bscan<<<1, 256, 0, stream>>>(bcnt, bbase);
    build_csr<<<NBUCK, 256, 0, stream>>>(bcnt, bbase, bbuf, rp, csr);

    // --- prep: weights + feature bf16 ---
    wprep<<<4, 256, 0, stream>>>(W1_rates, W1_rev, W2_rates, W2_rev, wtAll);
    cvt_bf<<<2048, 256, 0, stream>>>(x_user, x_item, A);

    int nbI = (NITEM + 63) / 64, nbU = (NUSER + 63) / 64;
    int nbAgg = (NTOT + 7) / 8;

    // --- layer 1: aggregate x, then h = leaky(agg@W1 + b1) (bf16, global-row in A) ---
    aggregate_bf<<<nbAgg, 256, 0, stream>>>(xu_bf, xi_bf, rp, csr, B);
    gemm_both<<<nbI + nbU, 256, 0, stream>>>(B, Wt1_rates, Wt1_rev, b1_rates, b1_rev,
                                             nullptr, nullptr, A, nbI, 1);

    // --- layer 2: aggregate h, then out = agg@W2 + b2 (fp32, direct to d_out) ---
    aggregate_bf<<<nbAgg, 256, 0, stream>>>(h_user, h_item, rp, csr, B);
    gemm_both<<<nbI + nbU, 256, 0, stream>>>(B, Wt2_rates, Wt2_rev, b2_rates, b2_rev,
                                             o_item, o_user, nullptr, nbI, 0);
}

// Round 11
// 230.344 us; speedup vs baseline: 1.8669x; 1.0389x over previous
//
#include <hip/hip_runtime.h>
#include <cstdint>
#include <cstddef>

#define NUSER 100000
#define NITEM 50000
#define NTOT  150000          // NITEM + NUSER (item rows first, then user rows)
#define NEDGE 500000
#define NEG_SLOPE 0.01f
#define PADW 136              // 128 + 8 bf16 pad (16B) -> conflict-free ds_read_b128

// ---- bucketed CSR build params ----
// Item rows: mean degree 10 (500k/50k); 512 rows * 10 = 5120 mean, sigma ~71 -> GCAP 8192 = +43 sigma.
#define BROWS 512                                  // rows per bucket
#define BSHIFT 9
#define NBUCK ((NTOT + BROWS - 1) / BROWS)         // 293
#define GCAP  8192                                 // global cap per bucket
#define EPB   2048                                 // edges per bin block (245 blocks -> ~1/CU)
#define NBINB ((NEDGE + EPB - 1) / EPB)            // 245
#define NENT  (2 * EPB)                            // 4096 entries per bin block

// ---- GEMM grid-stride params ----
#define NTILE_I ((NITEM + 63) / 64)                // 782
#define NTILE_U ((NUSER + 63) / 64)                // 1563
#define GBI 176                                    // item blocks (~4.4 tiles each)
#define GBU 352                                    // user blocks (~4.4 tiles each)

typedef __attribute__((ext_vector_type(8))) short bf16x8;
typedef __attribute__((ext_vector_type(4))) float f32x4;

__device__ __forceinline__ unsigned short f2bf(float f) {
    unsigned int u = __builtin_bit_cast(unsigned int, f);
    unsigned int r = u + 0x7fffu + ((u >> 16) & 1u);   // RNE
    return (unsigned short)(r >> 16);
}
__device__ __forceinline__ float bf2f(unsigned int b) {
    unsigned int u = (b & 0xffffu) << 16;
    return __builtin_bit_cast(float, u);
}
__device__ __forceinline__ unsigned int pack2(float lo, float hi) {
    return (unsigned int)f2bf(lo) | ((unsigned int)f2bf(hi) << 16);
}

// ---------------- CSR build phase 1: LDS-staged binning ----------------
// entry = (row & 511) << 17 | src    (src < 2^17, row_local < 2^9)

__global__ __launch_bounds__(256) void bin_edges(const int* __restrict__ src_rates, const int* __restrict__ dst_rates,
                                                 const int* __restrict__ src_rev,   const int* __restrict__ dst_rev,
                                                 int* __restrict__ bcnt, unsigned int* __restrict__ bbuf) {
    __shared__ int h[NBUCK];       // per-block bucket counts
    __shared__ int hs[NBUCK];      // staging segment start
    __shared__ int hbase[NBUCK];   // reserved global offset per bucket
    __shared__ int hcur[NBUCK];    // staging cursor
    __shared__ int bsc[256];
    __shared__ unsigned int stage[NENT];

    int t = threadIdx.x;
    int e0 = blockIdx.x * EPB;
    int n = NEDGE - e0; if (n > EPB) n = EPB;

    for (int i = t; i < NBUCK; i += 256) h[i] = 0;
    __syncthreads();

    // pass 1: count
    for (int i = t; i < n; i += 256) {
        int e = e0 + i;
        atomicAdd(&h[dst_rates[e] >> BSHIFT], 1);
        atomicAdd(&h[(NITEM + dst_rev[e]) >> BSHIFT], 1);
    }
    __syncthreads();

    // local exclusive scan over NBUCK (2 elements/thread) + reserve global segments
    int i0 = 2 * t, i1 = 2 * t + 1;
    int v0 = (i0 < NBUCK) ? h[i0] : 0;
    int v1 = (i1 < NBUCK) ? h[i1] : 0;
    int ls = v0 + v1;
    bsc[t] = ls;
    __syncthreads();
    for (int off = 1; off < 256; off <<= 1) {
        int x = (t >= off) ? bsc[t - off] : 0;
        __syncthreads();
        bsc[t] += x;
        __syncthreads();
    }
    int run = bsc[t] - ls;
    if (i0 < NBUCK) {
        hs[i0] = run; hcur[i0] = run;
        hbase[i0] = (v0 > 0) ? atomicAdd(&bcnt[i0], v0) : 0;
    }
    if (i1 < NBUCK) {
        hs[i1] = run + v0; hcur[i1] = run + v0;
        hbase[i1] = (v1 > 0) ? atomicAdd(&bcnt[i1], v1) : 0;
    }
    __syncthreads();

    // pass 2: scatter into LDS staging (bucket-sorted)
    for (int i = t; i < n; i += 256) {
        int e = e0 + i;
        int r1 = dst_rates[e];
        int p1 = atomicAdd(&hcur[r1 >> BSHIFT], 1);
        if (p1 < NENT)
            stage[p1] = ((unsigned)(r1 & (BROWS - 1)) << 17) | (unsigned)src_rates[e];
        int r2 = NITEM + dst_rev[e];
        int p2 = atomicAdd(&hcur[r2 >> BSHIFT], 1);
        if (p2 < NENT)
            stage[p2] = ((unsigned)(r2 & (BROWS - 1)) << 17) | (unsigned)src_rev[e];
    }
    __syncthreads();

    // flush: one wave per bucket (round-robin), contiguous coalesced writes
    int wid = t >> 6, lane = t & 63;
    for (int b = wid; b < NBUCK; b += 4) {
        int cnt = h[b];
        if (cnt > NENT) cnt = NENT;    // defensive clamp
        int gb = hbase[b];
        int sb = hs[b];
        for (int i = lane; i < cnt; i += 64) {
            int gpos = gb + i;
            if (gpos < GCAP) bbuf[(size_t)b * GCAP + gpos] = stage[sb + i];
        }
    }
}

// single block: exclusive scan of NBUCK bucket counts -> bbase (2 elements/thread)
__global__ __launch_bounds__(256) void bscan(const int* __restrict__ bcnt, int* __restrict__ bbase) {
    __shared__ int sm[256];
    int t = threadIdx.x;
    int i0 = 2 * t, i1 = 2 * t + 1;
    int v0 = (i0 < NBUCK) ? bcnt[i0] : 0;
    int v1 = (i1 < NBUCK) ? bcnt[i1] : 0;
    int ls = v0 + v1;
    sm[t] = ls;
    __syncthreads();
    for (int off = 1; off < 256; off <<= 1) {
        int x = (t >= off) ? sm[t - off] : 0;
        __syncthreads();
        sm[t] += x;
        __syncthreads();
    }
    int run = sm[t] - ls;
    if (i0 < NBUCK) bbase[i0] = run;
    if (i1 < NBUCK) bbase[i1] = run + v0;
}

// ---------------- CSR build phase 2: one block per bucket ----------------

__global__ __launch_bounds__(256) void build_csr(const int* __restrict__ bcnt, const int* __restrict__ bbase,
                                                 const unsigned int* __restrict__ bbuf,
                                                 int* __restrict__ rp, int* __restrict__ csr) {
    __shared__ unsigned int ent[GCAP];   // 32 KB
    __shared__ int h[BROWS], hs[BROWS];  // 4 KB
    __shared__ int bsc[256];

    int bk = blockIdx.x, t = threadIdx.x;
    int base = bbase[bk];
    int n = bcnt[bk];
    if (n > GCAP) n = GCAP;              // defensive (cannot trigger per capacity math)

    const unsigned int* src = bbuf + (size_t)bk * GCAP;
    for (int i = t; i < n; i += 256) ent[i] = src[i];
    h[t] = 0; h[t + 256] = 0;
    __syncthreads();

    for (int i = t; i < n; i += 256) atomicAdd(&h[ent[i] >> 17], 1);
    __syncthreads();

    int v0 = h[2 * t], v1 = h[2 * t + 1];
    int ls = v0 + v1;
    bsc[t] = ls;
    __syncthreads();
    for (int off = 1; off < 256; off <<= 1) {
        int x = (t >= off) ? bsc[t - off] : 0;
        __syncthreads();
        bsc[t] += x;
        __syncthreads();
    }
    int run = bsc[t] - ls;
    hs[2 * t] = run;
    hs[2 * t + 1] = run + v0;
    __syncthreads();

    for (int r = t; r < BROWS; r += 256) {
        int row = bk * BROWS + r;
        if (row < NTOT) rp[row] = base + hs[r];
        h[r] = 0;
    }
    if (bk == 0 && t == 0) rp[NTOT] = 2 * NEDGE;
    __syncthreads();

    for (int i = t; i < n; i += 256) {
        unsigned int ev = ent[i];
        int rl = (int)(ev >> 17);
        int pos = base + hs[rl] + atomicAdd(&h[rl], 1);
        csr[pos] = (int)(ev & 0x1FFFFu);
    }
}

// ---------------- weight prep: W[128][128] fp32 -> Wt bf16 [col][k] padded PADW ----------------

__global__ void wprep(const float* __restrict__ w0, const float* __restrict__ w1,
                      const float* __restrict__ w2, const float* __restrict__ w3,
                      unsigned short* __restrict__ wt) {
    const float* src = (blockIdx.x == 0) ? w0 : (blockIdx.x == 1) ? w1 : (blockIdx.x == 2) ? w2 : w3;
    unsigned short* dst = wt + (size_t)blockIdx.x * 128 * PADW;
    for (int i = threadIdx.x; i < 16384; i += 256) {
        int k = i >> 7, c = i & 127;
        dst[c * PADW + k] = f2bf(src[i]);
    }
}

// ---------------- x -> bf16 convert ----------------

__global__ void cvt_bf(const float* __restrict__ xu, const float* __restrict__ xi,
                       unsigned short* __restrict__ dst) {
    const int n8u = NUSER * 128 / 8;
    const int n8  = (NUSER + NITEM) * 128 / 8;
    for (int i = blockIdx.x * blockDim.x + threadIdx.x; i < n8; i += gridDim.x * blockDim.x) {
        const float* s = (i < n8u) ? (xu + (size_t)i * 8) : (xi + (size_t)(i - n8u) * 8);
        float4 a = ((const float4*)s)[0];
        float4 b = ((const float4*)s)[1];
        uint4 o;
        o.x = pack2(a.x, a.y);
        o.y = pack2(a.z, a.w);
        o.z = pack2(b.x, b.y);
        o.w = pack2(b.z, b.w);
        ((uint4*)dst)[i] = o;
    }
}

// ---------------- aggregation (bf16 in -> bf16 out), both relations, 2x-unrolled gather ----------------

__global__ __launch_bounds__(256) void aggregate_bf(const unsigned short* __restrict__ featA,  // item rows
                                                    const unsigned short* __restrict__ featB,  // user rows
                                                    const int* __restrict__ rp, const int* __restrict__ csr,
                                                    unsigned short* __restrict__ outb) {
    int row = blockIdx.x * 8 + (threadIdx.x >> 5);
    if (row >= NTOT) return;
    const unsigned short* feat = (row < NITEM) ? featA : featB;
    int l = threadIdx.x & 31;
    int sub = l >> 4, l16 = l & 15;
    int b = rp[row], e = rp[row + 1];
    float a0 = 0.f, a1 = 0.f, a2 = 0.f, a3 = 0.f, a4 = 0.f, a5 = 0.f, a6 = 0.f, a7 = 0.f;
    int j = b + sub;
    // 2 independent gathers in flight per half-wave sub (4 edges/row total in flight)
    for (; j + 2 < e; j += 4) {
        int s0 = csr[j];
        int s1 = csr[j + 2];
        uint4 v0 = *((const uint4*)(feat + (size_t)s0 * 128) + l16);
        uint4 v1 = *((const uint4*)(feat + (size_t)s1 * 128) + l16);
        a0 += bf2f(v0.x); a1 += bf2f(v0.x >> 16);
        a2 += bf2f(v0.y); a3 += bf2f(v0.y >> 16);
        a4 += bf2f(v0.z); a5 += bf2f(v0.z >> 16);
        a6 += bf2f(v0.w); a7 += bf2f(v0.w >> 16);
        a0 += bf2f(v1.x); a1 += bf2f(v1.x >> 16);
        a2 += bf2f(v1.y); a3 += bf2f(v1.y >> 16);
        a4 += bf2f(v1.z); a5 += bf2f(v1.z >> 16);
        a6 += bf2f(v1.w); a7 += bf2f(v1.w >> 16);
    }
    if (j < e) {
        int s0 = csr[j];
        uint4 v0 = *((const uint4*)(feat + (size_t)s0 * 128) + l16);
        a0 += bf2f(v0.x); a1 += bf2f(v0.x >> 16);
        a2 += bf2f(v0.y); a3 += bf2f(v0.y >> 16);
        a4 += bf2f(v0.z); a5 += bf2f(v0.z >> 16);
        a6 += bf2f(v0.w); a7 += bf2f(v0.w >> 16);
    }
    a0 += __shfl_xor(a0, 16); a1 += __shfl_xor(a1, 16);
    a2 += __shfl_xor(a2, 16); a3 += __shfl_xor(a3, 16);
    a4 += __shfl_xor(a4, 16); a5 += __shfl_xor(a5, 16);
    a6 += __shfl_xor(a6, 16); a7 += __shfl_xor(a7, 16);
    if (sub == 0) {
        int deg = e - b;
        float inv = 1.0f / (float)(deg > 0 ? deg : 1);
        uint4 o;
        o.x = pack2(a0 * inv, a1 * inv);
        o.y = pack2(a2 * inv, a3 * inv);
        o.z = pack2(a4 * inv, a5 * inv);
        o.w = pack2(a6 * inv, a7 * inv);
        *((uint4*)(outb + (size_t)row * 128) + l16) = o;
    }
}

// ---------------- MFMA GEMM, both regions, grid-stride tiles (W staged once per block) ----------------
// blocks [0, GBI) -> item tiles (stride GBI); blocks [GBI, GBI+GBU) -> user tiles (stride GBU).
// fp32 path (outB == nullptr): region-local row indexing into outFI/outFU.
// bf16 path: global-row indexed outB.

__global__ __launch_bounds__(256) void gemm_both(const unsigned short* __restrict__ in,
                                                 const unsigned short* __restrict__ wtI,
                                                 const unsigned short* __restrict__ wtU,
                                                 const float* __restrict__ bI,
                                                 const float* __restrict__ bU,
                                                 float* __restrict__ outFI, float* __restrict__ outFU,
                                                 unsigned short* __restrict__ outB,
                                                 int leaky) {
    __shared__ __attribute__((aligned(16))) unsigned short wl[128 * PADW];
    __shared__ __attribute__((aligned(16))) unsigned short xl[64 * PADW];
    int t = threadIdx.x;
    int bi = blockIdx.x;
    bool item = bi < GBI;
    int tbeg = item ? bi : bi - GBI;
    int nT   = item ? NTILE_I : NTILE_U;
    int gstr = item ? GBI : GBU;
    int rbeg = item ? 0 : NITEM;
    int Nend = item ? NITEM : NTOT;
    const unsigned short* wt = item ? wtI : wtU;
    const float* bias = item ? bI : bU;
    float* oF = item ? outFI : outFU;

    // stage W once per block
    for (int i = t; i < 128 * PADW / 8; i += 256)
        ((uint4*)wl)[i] = ((const uint4*)wt)[i];

    int lane = t & 63, w = t >> 6;
    int l16 = lane & 15, kq = lane >> 4;
    int rowb = w * 16;

    float bv[8];
    #pragma unroll
    for (int t8 = 0; t8 < 8; ++t8) bv[t8] = bias[t8 * 16 + l16];

    for (int tt = tbeg; tt < nT; tt += gstr) {
        int row0 = rbeg + tt * 64;

        __syncthreads();   // previous iteration's xl readers done (iter 0: orders wl too)
        for (int i = t; i < 1024; i += 256) {
            int r = i >> 4, c = i & 15;
            int row = row0 + r;
            uint4 v = make_uint4(0u, 0u, 0u, 0u);
            if (row < Nend) v = ((const uint4*)(in + (size_t)row * 128))[c];
            ((uint4*)xl)[r * (PADW / 8) + c] = v;
        }
        __syncthreads();

        f32x4 acc[8];
        #pragma unroll
        for (int i = 0; i < 8; ++i) acc[i] = (f32x4){0.f, 0.f, 0.f, 0.f};

        #pragma unroll
        for (int ks = 0; ks < 4; ++ks) {
            int ko = ks * 32 + kq * 8;
            bf16x8 af = *(const bf16x8*)&xl[(rowb + l16) * PADW + ko];
            #pragma unroll
            for (int t8 = 0; t8 < 8; ++t8) {
                bf16x8 bf = *(const bf16x8*)&wl[(t8 * 16 + l16) * PADW + ko];
                acc[t8] = __builtin_amdgcn_mfma_f32_16x16x32_bf16(af, bf, acc[t8], 0, 0, 0);
            }
        }

        if (outB == nullptr) {
            #pragma unroll
            for (int t8 = 0; t8 < 8; ++t8) {
                #pragma unroll
                for (int j = 0; j < 4; ++j) {
                    int row = row0 + rowb + kq * 4 + j;
                    if (row < Nend) {
                        float v = acc[t8][j] + bv[t8];
                        if (leaky) v = v > 0.f ? v : NEG_SLOPE * v;
                        oF[(size_t)(row - rbeg) * 128 + t8 * 16 + l16] = v;
                    }
                }
            }
        } else {
            #pragma unroll
            for (int t8 = 0; t8 < 8; ++t8) {
                #pragma unroll
                for (int j = 0; j < 4; ++j) {
                    float v = acc[t8][j] + bv[t8];
                    if (leaky) v = v > 0.f ? v : NEG_SLOPE * v;
                    xl[(rowb + kq * 4 + j) * PADW + t8 * 16 + l16] = f2bf(v);
                }
            }
            __syncthreads();
            for (int i = t; i < 1024; i += 256) {
                int r = i >> 4, c = i & 15;
                int row = row0 + r;
                if (row < Nend)
                    ((uint4*)(outB + (size_t)row * 128))[c] = ((uint4*)xl)[r * (PADW / 8) + c];
            }
        }
    }
}

// ---------------- launch ----------------

extern "C" void kernel_launch(void* const* d_in, const int* in_sizes, int n_in,
                              void* d_out, int out_size, void* d_ws, size_t ws_size,
                              hipStream_t stream) {
    const float* x_user    = (const float*)d_in[0];
    const float* x_item    = (const float*)d_in[1];
    const int*   src_rates = (const int*)d_in[2];
    const int*   dst_rates = (const int*)d_in[3];
    const int*   src_rev   = (const int*)d_in[4];
    const int*   dst_rev   = (const int*)d_in[5];
    const float* W1_rates  = (const float*)d_in[6];
    const float* b1_rates  = (const float*)d_in[7];
    const float* W1_rev    = (const float*)d_in[8];
    const float* b1_rev    = (const float*)d_in[9];
    const float* W2_rates  = (const float*)d_in[10];
    const float* b2_rates  = (const float*)d_in[11];
    const float* W2_rev    = (const float*)d_in[12];
    const float* b2_rev    = (const float*)d_in[13];

    float* out    = (float*)d_out;
    float* o_user = out;                          // [NUSER,128] fp32
    float* o_item = out + (size_t)NUSER * 128;    // [NITEM,128] fp32

    char* ws = (char*)d_ws;
    size_t off = 0;
    auto carve = [&](size_t bytes) -> void* {
        void* p = ws + off;
        off = (off + bytes + 255) & ~(size_t)255;
        return p;
    };
    // A: first x_bf {xu[NU],xi[NI]}, later h {h_item[NI], h_user[NU]} (global-row indexed)
    unsigned short* A = (unsigned short*)carve((size_t)NTOT * 128 * 2);
    // B: aggregate output; overlaid by bucket buffer during CSR build (9.6MB < 38.4MB)
    unsigned short* B = (unsigned short*)carve((size_t)NTOT * 128 * 2);
    int* rp    = (int*)carve((size_t)(NTOT + 1) * 4);
    int* bcnt  = (int*)carve((size_t)NBUCK * 4);
    int* bbase = (int*)carve((size_t)NBUCK * 4);
    int* csr   = (int*)carve((size_t)(2 * NEDGE) * 4);
    unsigned short* wtAll = (unsigned short*)carve((size_t)4 * 128 * PADW * 2);
    unsigned short* Wt1_rates = wtAll;
    unsigned short* Wt1_rev   = wtAll + 1 * (size_t)128 * PADW;
    unsigned short* Wt2_rates = wtAll + 2 * (size_t)128 * PADW;
    unsigned short* Wt2_rev   = wtAll + 3 * (size_t)128 * PADW;

    unsigned int* bbuf = (unsigned int*)B;        // overlay: consumed before aggregate writes B

    unsigned short* xu_bf = A;
    unsigned short* xi_bf = A + (size_t)NUSER * 128;
    unsigned short* h_item = A;
    unsigned short* h_user = A + (size_t)NITEM * 128;

    // --- CSR build (LDS-staged bucketed counting sort) ---
    hipMemsetAsync(bcnt, 0, (size_t)NBUCK * 4, stream);
    bin_edges<<<NBINB, 256, 0, stream>>>(src_rates, dst_rates, src_rev, dst_rev, bcnt, bbuf);
    bscan<<<1, 256, 0, stream>>>(bcnt, bbase);
    build_csr<<<NBUCK, 256, 0, stream>>>(bcnt, bbase, bbuf, rp, csr);

    // --- prep: weights + feature bf16 ---
    wprep<<<4, 256, 0, stream>>>(W1_rates, W1_rev, W2_rates, W2_rev, wtAll);
    cvt_bf<<<2048, 256, 0, stream>>>(x_user, x_item, A);

    int nbAgg = (NTOT + 7) / 8;

    // --- layer 1: aggregate x, then h = leaky(agg@W1 + b1) (bf16, global-row in A) ---
    aggregate_bf<<<nbAgg, 256, 0, stream>>>(xu_bf, xi_bf, rp, csr, B);
    gemm_both<<<GBI + GBU, 256, 0, stream>>>(B, Wt1_rates, Wt1_rev, b1_rates, b1_rev,
                                             nullptr, nullptr, A, 1);

    // --- layer 2: aggregate h, then out = agg@W2 + b2 (fp32, direct to d_out) ---
    aggregate_bf<<<nbAgg, 256, 0, stream>>>(h_user, h_item, rp, csr, B);
    gemm_both<<<GBI + GBU, 256, 0, stream>>>(B, Wt2_rates, Wt2_rev, b2_rates, b2_rev,
                                             o_item, o_user, nullptr, 0);
}

// Round 12
// 213.750 us; speedup vs baseline: 2.0118x; 1.0776x over previous
//
#include <hip/hip_runtime.h>
#include <cstdint>
#include <cstddef>

#define NUSER 100000
#define NITEM 50000
#define NTOT  150000          // NITEM + NUSER (item rows first, then user rows)
#define NEDGE 500000
#define NEG_SLOPE 0.01f
#define PADW 136              // 128 + 8 bf16 pad (16B) -> conflict-free ds_read_b128

// ---- bucketed CSR build params ----
// Item rows: mean degree 10 (500k/50k); 512 rows * 10 = 5120 mean, sigma ~71 -> GCAP 8192 = +43 sigma.
#define BROWS 512                                  // rows per bucket
#define BSHIFT 9
#define NBUCK ((NTOT + BROWS - 1) / BROWS)         // 293
#define GCAP  8192                                 // global cap per bucket
#define EPB   2048                                 // edges per bin block
#define NBINB ((NEDGE + EPB - 1) / EPB)            // 245
#define NENT  (2 * EPB)                            // 4096 entries per bin block

// ---- GEMM grid-stride params ----
#define NTILE_I ((NITEM + 63) / 64)                // 782
#define NTILE_U ((NUSER + 63) / 64)                // 1563
#define GBI 176                                    // item blocks (~4.4 tiles each)
#define GBU 352                                    // user blocks (~4.4 tiles each)

typedef __attribute__((ext_vector_type(8))) short bf16x8;
typedef __attribute__((ext_vector_type(4))) float f32x4;

__device__ __forceinline__ unsigned short f2bf(float f) {
    unsigned int u = __builtin_bit_cast(unsigned int, f);
    unsigned int r = u + 0x7fffu + ((u >> 16) & 1u);   // RNE
    return (unsigned short)(r >> 16);
}
__device__ __forceinline__ float bf2f(unsigned int b) {
    unsigned int u = (b & 0xffffu) << 16;
    return __builtin_bit_cast(float, u);
}
__device__ __forceinline__ unsigned int pack2(float lo, float hi) {
    return (unsigned int)f2bf(lo) | ((unsigned int)f2bf(hi) << 16);
}

// ---------------- CSR build phase 1: LDS-staged binning (512 threads: 2 waves/SIMD) ----------------
// entry = (row & 511) << 17 | src    (src < 2^17, row_local < 2^9)

__global__ __launch_bounds__(512) void bin_edges(const int* __restrict__ src_rates, const int* __restrict__ dst_rates,
                                                 const int* __restrict__ src_rev,   const int* __restrict__ dst_rev,
                                                 int* __restrict__ bcnt, unsigned int* __restrict__ bbuf) {
    __shared__ int h[NBUCK];       // per-block bucket counts
    __shared__ int hs[NBUCK];      // staging segment start
    __shared__ int hbase[NBUCK];   // reserved global offset per bucket
    __shared__ int hcur[NBUCK];    // staging cursor
    __shared__ int bsc[512];
    __shared__ unsigned int stage[NENT];

    int t = threadIdx.x;
    int e0 = blockIdx.x * EPB;
    int n = NEDGE - e0; if (n > EPB) n = EPB;

    for (int i = t; i < NBUCK; i += 512) h[i] = 0;
    __syncthreads();

    // pass 1: count
    for (int i = t; i < n; i += 512) {
        int e = e0 + i;
        atomicAdd(&h[dst_rates[e] >> BSHIFT], 1);
        atomicAdd(&h[(NITEM + dst_rev[e]) >> BSHIFT], 1);
    }
    __syncthreads();

    // local exclusive scan over NBUCK (1 element/thread, NBUCK <= 512) + reserve global segments
    int v = (t < NBUCK) ? h[t] : 0;
    bsc[t] = v;
    __syncthreads();
    for (int off = 1; off < 512; off <<= 1) {
        int x = (t >= off) ? bsc[t - off] : 0;
        __syncthreads();
        bsc[t] += x;
        __syncthreads();
    }
    if (t < NBUCK) {
        int run = bsc[t] - v;
        hs[t] = run;
        hcur[t] = run;
        hbase[t] = (v > 0) ? atomicAdd(&bcnt[t], v) : 0;
    }
    __syncthreads();

    // pass 2: scatter into LDS staging (bucket-sorted)
    for (int i = t; i < n; i += 512) {
        int e = e0 + i;
        int r1 = dst_rates[e];
        int p1 = atomicAdd(&hcur[r1 >> BSHIFT], 1);
        if (p1 < NENT)
            stage[p1] = ((unsigned)(r1 & (BROWS - 1)) << 17) | (unsigned)src_rates[e];
        int r2 = NITEM + dst_rev[e];
        int p2 = atomicAdd(&hcur[r2 >> BSHIFT], 1);
        if (p2 < NENT)
            stage[p2] = ((unsigned)(r2 & (BROWS - 1)) << 17) | (unsigned)src_rev[e];
    }
    __syncthreads();

    // flush: one wave per bucket (round-robin over 8 waves), contiguous coalesced writes
    int wid = t >> 6, lane = t & 63;
    for (int b = wid; b < NBUCK; b += 8) {
        int cnt = h[b];
        if (cnt > NENT) cnt = NENT;    // defensive clamp
        int gb = hbase[b];
        int sb = hs[b];
        for (int i = lane; i < cnt; i += 64) {
            int gpos = gb + i;
            if (gpos < GCAP) bbuf[(size_t)b * GCAP + gpos] = stage[sb + i];
        }
    }
}

// single block: exclusive scan of NBUCK bucket counts -> bbase (2 elements/thread)
__global__ __launch_bounds__(256) void bscan(const int* __restrict__ bcnt, int* __restrict__ bbase) {
    __shared__ int sm[256];
    int t = threadIdx.x;
    int i0 = 2 * t, i1 = 2 * t + 1;
    int v0 = (i0 < NBUCK) ? bcnt[i0] : 0;
    int v1 = (i1 < NBUCK) ? bcnt[i1] : 0;
    int ls = v0 + v1;
    sm[t] = ls;
    __syncthreads();
    for (int off = 1; off < 256; off <<= 1) {
        int x = (t >= off) ? sm[t - off] : 0;
        __syncthreads();
        sm[t] += x;
        __syncthreads();
    }
    int run = sm[t] - ls;
    if (i0 < NBUCK) bbase[i0] = run;
    if (i1 < NBUCK) bbase[i1] = run + v0;
}

// ---------------- CSR build phase 2: one block per bucket ----------------

__global__ __launch_bounds__(256) void build_csr(const int* __restrict__ bcnt, const int* __restrict__ bbase,
                                                 const unsigned int* __restrict__ bbuf,
                                                 int* __restrict__ rp, int* __restrict__ csr) {
    __shared__ unsigned int ent[GCAP];   // 32 KB
    __shared__ int h[BROWS], hs[BROWS];  // 4 KB
    __shared__ int bsc[256];

    int bk = blockIdx.x, t = threadIdx.x;
    int base = bbase[bk];
    int n = bcnt[bk];
    if (n > GCAP) n = GCAP;              // defensive (cannot trigger per capacity math)

    const unsigned int* src = bbuf + (size_t)bk * GCAP;
    for (int i = t; i < n; i += 256) ent[i] = src[i];
    h[t] = 0; h[t + 256] = 0;
    __syncthreads();

    for (int i = t; i < n; i += 256) atomicAdd(&h[ent[i] >> 17], 1);
    __syncthreads();

    int v0 = h[2 * t], v1 = h[2 * t + 1];
    int ls = v0 + v1;
    bsc[t] = ls;
    __syncthreads();
    for (int off = 1; off < 256; off <<= 1) {
        int x = (t >= off) ? bsc[t - off] : 0;
        __syncthreads();
        bsc[t] += x;
        __syncthreads();
    }
    int run = bsc[t] - ls;
    hs[2 * t] = run;
    hs[2 * t + 1] = run + v0;
    __syncthreads();

    for (int r = t; r < BROWS; r += 256) {
        int row = bk * BROWS + r;
        if (row < NTOT) rp[row] = base + hs[r];
        h[r] = 0;
    }
    if (bk == 0 && t == 0) rp[NTOT] = 2 * NEDGE;
    __syncthreads();

    for (int i = t; i < n; i += 256) {
        unsigned int ev = ent[i];
        int rl = (int)(ev >> 17);
        int pos = base + hs[rl] + atomicAdd(&h[rl], 1);
        csr[pos] = (int)(ev & 0x1FFFFu);
    }
}

// ---------------- weight prep: W[128][128] fp32 -> Wt bf16 [col][k] padded PADW ----------------

__global__ void wprep(const float* __restrict__ w0, const float* __restrict__ w1,
                      const float* __restrict__ w2, const float* __restrict__ w3,
                      unsigned short* __restrict__ wt) {
    const float* src = (blockIdx.x == 0) ? w0 : (blockIdx.x == 1) ? w1 : (blockIdx.x == 2) ? w2 : w3;
    unsigned short* dst = wt + (size_t)blockIdx.x * 128 * PADW;
    for (int i = threadIdx.x; i < 16384; i += 256) {
        int k = i >> 7, c = i & 127;
        dst[c * PADW + k] = f2bf(src[i]);
    }
}

// ---------------- x -> bf16 convert ----------------

__global__ void cvt_bf(const float* __restrict__ xu, const float* __restrict__ xi,
                       unsigned short* __restrict__ dst) {
    const int n8u = NUSER * 128 / 8;
    const int n8  = (NUSER + NITEM) * 128 / 8;
    for (int i = blockIdx.x * blockDim.x + threadIdx.x; i < n8; i += gridDim.x * blockDim.x) {
        const float* s = (i < n8u) ? (xu + (size_t)i * 8) : (xi + (size_t)(i - n8u) * 8);
        float4 a = ((const float4*)s)[0];
        float4 b = ((const float4*)s)[1];
        uint4 o;
        o.x = pack2(a.x, a.y);
        o.y = pack2(a.z, a.w);
        o.z = pack2(b.x, b.y);
        o.w = pack2(b.z, b.w);
        ((uint4*)dst)[i] = o;
    }
}

// ---------------- aggregation (bf16 in -> bf16 out), both relations, 2x-unrolled gather ----------------

__global__ __launch_bounds__(256) void aggregate_bf(const unsigned short* __restrict__ featA,  // item rows
                                                    const unsigned short* __restrict__ featB,  // user rows
                                                    const int* __restrict__ rp, const int* __restrict__ csr,
                                                    unsigned short* __restrict__ outb) {
    int row = blockIdx.x * 8 + (threadIdx.x >> 5);
    if (row >= NTOT) return;
    const unsigned short* feat = (row < NITEM) ? featA : featB;
    int l = threadIdx.x & 31;
    int sub = l >> 4, l16 = l & 15;
    int b = rp[row], e = rp[row + 1];
    float a0 = 0.f, a1 = 0.f, a2 = 0.f, a3 = 0.f, a4 = 0.f, a5 = 0.f, a6 = 0.f, a7 = 0.f;
    int j = b + sub;
    // 2 independent gathers in flight per half-wave sub (4 edges/row total in flight)
    for (; j + 2 < e; j += 4) {
        int s0 = csr[j];
        int s1 = csr[j + 2];
        uint4 v0 = *((const uint4*)(feat + (size_t)s0 * 128) + l16);
        uint4 v1 = *((const uint4*)(feat + (size_t)s1 * 128) + l16);
        a0 += bf2f(v0.x); a1 += bf2f(v0.x >> 16);
        a2 += bf2f(v0.y); a3 += bf2f(v0.y >> 16);
        a4 += bf2f(v0.z); a5 += bf2f(v0.z >> 16);
        a6 += bf2f(v0.w); a7 += bf2f(v0.w >> 16);
        a0 += bf2f(v1.x); a1 += bf2f(v1.x >> 16);
        a2 += bf2f(v1.y); a3 += bf2f(v1.y >> 16);
        a4 += bf2f(v1.z); a5 += bf2f(v1.z >> 16);
        a6 += bf2f(v1.w); a7 += bf2f(v1.w >> 16);
    }
    if (j < e) {
        int s0 = csr[j];
        uint4 v0 = *((const uint4*)(feat + (size_t)s0 * 128) + l16);
        a0 += bf2f(v0.x); a1 += bf2f(v0.x >> 16);
        a2 += bf2f(v0.y); a3 += bf2f(v0.y >> 16);
        a4 += bf2f(v0.z); a5 += bf2f(v0.z >> 16);
        a6 += bf2f(v0.w); a7 += bf2f(v0.w >> 16);
    }
    a0 += __shfl_xor(a0, 16); a1 += __shfl_xor(a1, 16);
    a2 += __shfl_xor(a2, 16); a3 += __shfl_xor(a3, 16);
    a4 += __shfl_xor(a4, 16); a5 += __shfl_xor(a5, 16);
    a6 += __shfl_xor(a6, 16); a7 += __shfl_xor(a7, 16);
    if (sub == 0) {
        int deg = e - b;
        float inv = 1.0f / (float)(deg > 0 ? deg : 1);
        uint4 o;
        o.x = pack2(a0 * inv, a1 * inv);
        o.y = pack2(a2 * inv, a3 * inv);
        o.z = pack2(a4 * inv, a5 * inv);
        o.w = pack2(a6 * inv, a7 * inv);
        *((uint4*)(outb + (size_t)row * 128) + l16) = o;
    }
}

// ---------------- MFMA GEMM, both regions, grid-stride tiles (W staged once per block) ----------------
// blocks [0, GBI) -> item tiles (stride GBI); blocks [GBI, GBI+GBU) -> user tiles (stride GBU).
// fp32 path (outB == nullptr): region-local row indexing into outFI/outFU.
// bf16 path: global-row indexed outB.

__global__ __launch_bounds__(256) void gemm_both(const unsigned short* __restrict__ in,
                                                 const unsigned short* __restrict__ wtI,
                                                 const unsigned short* __restrict__ wtU,
                                                 const float* __restrict__ bI,
                                                 const float* __restrict__ bU,
                                                 float* __restrict__ outFI, float* __restrict__ outFU,
                                                 unsigned short* __restrict__ outB,
                                                 int leaky) {
    __shared__ __attribute__((aligned(16))) unsigned short wl[128 * PADW];
    __shared__ __attribute__((aligned(16))) unsigned short xl[64 * PADW];
    int t = threadIdx.x;
    int bi = blockIdx.x;
    bool item = bi < GBI;
    int tbeg = item ? bi : bi - GBI;
    int nT   = item ? NTILE_I : NTILE_U;
    int gstr = item ? GBI : GBU;
    int rbeg = item ? 0 : NITEM;
    int Nend = item ? NITEM : NTOT;
    const unsigned short* wt = item ? wtI : wtU;
    const float* bias = item ? bI : bU;
    float* oF = item ? outFI : outFU;

    // stage W once per block
    for (int i = t; i < 128 * PADW / 8; i += 256)
        ((uint4*)wl)[i] = ((const uint4*)wt)[i];

    int lane = t & 63, w = t >> 6;
    int l16 = lane & 15, kq = lane >> 4;
    int rowb = w * 16;

    float bv[8];
    #pragma unroll
    for (int t8 = 0; t8 < 8; ++t8) bv[t8] = bias[t8 * 16 + l16];

    for (int tt = tbeg; tt < nT; tt += gstr) {
        int row0 = rbeg + tt * 64;

        __syncthreads();   // previous iteration's xl readers done (iter 0: orders wl too)
        for (int i = t; i < 1024; i += 256) {
            int r = i >> 4, c = i & 15;
            int row = row0 + r;
            uint4 v = make_uint4(0u, 0u, 0u, 0u);
            if (row < Nend) v = ((const uint4*)(in + (size_t)row * 128))[c];
            ((uint4*)xl)[r * (PADW / 8) + c] = v;
        }
        __syncthreads();

        f32x4 acc[8];
        #pragma unroll
        for (int i = 0; i < 8; ++i) acc[i] = (f32x4){0.f, 0.f, 0.f, 0.f};

        #pragma unroll
        for (int ks = 0; ks < 4; ++ks) {
            int ko = ks * 32 + kq * 8;
            bf16x8 af = *(const bf16x8*)&xl[(rowb + l16) * PADW + ko];
            #pragma unroll
            for (int t8 = 0; t8 < 8; ++t8) {
                bf16x8 bf = *(const bf16x8*)&wl[(t8 * 16 + l16) * PADW + ko];
                acc[t8] = __builtin_amdgcn_mfma_f32_16x16x32_bf16(af, bf, acc[t8], 0, 0, 0);
            }
        }

        if (outB == nullptr) {
            #pragma unroll
            for (int t8 = 0; t8 < 8; ++t8) {
                #pragma unroll
                for (int j = 0; j < 4; ++j) {
                    int row = row0 + rowb + kq * 4 + j;
                    if (row < Nend) {
                        float v = acc[t8][j] + bv[t8];
                        if (leaky) v = v > 0.f ? v : NEG_SLOPE * v;
                        oF[(size_t)(row - rbeg) * 128 + t8 * 16 + l16] = v;
                    }
                }
            }
        } else {
            #pragma unroll
            for (int t8 = 0; t8 < 8; ++t8) {
                #pragma unroll
                for (int j = 0; j < 4; ++j) {
                    float v = acc[t8][j] + bv[t8];
                    if (leaky) v = v > 0.f ? v : NEG_SLOPE * v;
                    xl[(rowb + kq * 4 + j) * PADW + t8 * 16 + l16] = f2bf(v);
                }
            }
            __syncthreads();
            for (int i = t; i < 1024; i += 256) {
                int r = i >> 4, c = i & 15;
                int row = row0 + r;
                if (row < Nend)
                    ((uint4*)(outB + (size_t)row * 128))[c] = ((uint4*)xl)[r * (PADW / 8) + c];
            }
        }
    }
}

// ---------------- launch ----------------

extern "C" void kernel_launch(void* const* d_in, const int* in_sizes, int n_in,
                              void* d_out, int out_size, void* d_ws, size_t ws_size,
                              hipStream_t stream) {
    const float* x_user    = (const float*)d_in[0];
    const float* x_item    = (const float*)d_in[1];
    const int*   src_rates = (const int*)d_in[2];
    const int*   dst_rates = (const int*)d_in[3];
    const int*   src_rev   = (const int*)d_in[4];
    const int*   dst_rev   = (const int*)d_in[5];
    const float* W1_rates  = (const float*)d_in[6];
    const float* b1_rates  = (const float*)d_in[7];
    const float* W1_rev    = (const float*)d_in[8];
    const float* b1_rev    = (const float*)d_in[9];
    const float* W2_rates  = (const float*)d_in[10];
    const float* b2_rates  = (const float*)d_in[11];
    const float* W2_rev    = (const float*)d_in[12];
    const float* b2_rev    = (const float*)d_in[13];

    float* out    = (float*)d_out;
    float* o_user = out;                          // [NUSER,128] fp32
    float* o_item = out + (size_t)NUSER * 128;    // [NITEM,128] fp32

    char* ws = (char*)d_ws;
    size_t off = 0;
    auto carve = [&](size_t bytes) -> void* {
        void* p = ws + off;
        off = (off + bytes + 255) & ~(size_t)255;
        return p;
    };
    // A: first x_bf {xu[NU],xi[NI]}, later h {h_item[NI], h_user[NU]} (global-row indexed)
    unsigned short* A = (unsigned short*)carve((size_t)NTOT * 128 * 2);
    // B: aggregate output; overlaid by bucket buffer during CSR build (9.6MB < 38.4MB)
    unsigned short* B = (unsigned short*)carve((size_t)NTOT * 128 * 2);
    int* rp    = (int*)carve((size_t)(NTOT + 1) * 4);
    int* bcnt  = (int*)carve((size_t)NBUCK * 4);
    int* bbase = (int*)carve((size_t)NBUCK * 4);
    int* csr   = (int*)carve((size_t)(2 * NEDGE) * 4);
    unsigned short* wtAll = (unsigned short*)carve((size_t)4 * 128 * PADW * 2);
    unsigned short* Wt1_rates = wtAll;
    unsigned short* Wt1_rev   = wtAll + 1 * (size_t)128 * PADW;
    unsigned short* Wt2_rates = wtAll + 2 * (size_t)128 * PADW;
    unsigned short* Wt2_rev   = wtAll + 3 * (size_t)128 * PADW;

    unsigned int* bbuf = (unsigned int*)B;        // overlay: consumed before aggregate writes B

    unsigned short* xu_bf = A;
    unsigned short* xi_bf = A + (size_t)NUSER * 128;
    unsigned short* h_item = A;
    unsigned short* h_user = A + (size_t)NITEM * 128;

    // --- CSR build (LDS-staged bucketed counting sort) ---
    hipMemsetAsync(bcnt, 0, (size_t)NBUCK * 4, stream);
    bin_edges<<<NBINB, 512, 0, stream>>>(src_rates, dst_rates, src_rev, dst_rev, bcnt, bbuf);
    bscan<<<1, 256, 0, stream>>>(bcnt, bbase);
    build_csr<<<NBUCK, 256, 0, stream>>>(bcnt, bbase, bbuf, rp, csr);

    // --- prep: weights + feature bf16 ---
    wprep<<<4, 256, 0, stream>>>(W1_rates, W1_rev, W2_rates, W2_rev, wtAll);
    cvt_bf<<<2048, 256, 0, stream>>>(x_user, x_item, A);

    int nbAgg = (NTOT + 7) / 8;

    // --- layer 1: aggregate x, then h = leaky(agg@W1 + b1) (bf16, global-row in A) ---
    aggregate_bf<<<nbAgg, 256, 0, stream>>>(xu_bf, xi_bf, rp, csr, B);
    gemm_both<<<GBI + GBU, 256, 0, stream>>>(B, Wt1_rates, Wt1_rev, b1_rates, b1_rev,
                                             nullptr, nullptr, A, 1);

    // --- layer 2: aggregate h, then out = agg@W2 + b2 (fp32, direct to d_out) ---
    aggregate_bf<<<nbAgg, 256, 0, stream>>>(h_user, h_item, rp, csr, B);
    gemm_both<<<GBI + GBU, 256, 0, stream>>>(B, Wt2_rates, Wt2_rev, b2_rates, b2_rev,
                                             o_item, o_user, nullptr, 0);
}